// Round 7
// baseline (1503.749 us; speedup 1.0000x reference)
//
#include <hip/hip_runtime.h>
#include <cstdint>
#include <cstddef>

typedef short bf16x8 __attribute__((ext_vector_type(8)));
typedef float f32x4 __attribute__((ext_vector_type(4)));

__device__ __forceinline__ float sigf(float x) { return 1.0f / (1.0f + __expf(-x)); }
__device__ __forceinline__ float tanhfast(float x) {
  float e = __expf(-2.0f * fabsf(x));
  float t = (1.0f - e) / (1.0f + e);
  return copysignf(t, x);
}
__device__ __forceinline__ unsigned short f2bf(float f) {
  unsigned int u = __float_as_uint(f);
  u = (u + 0x7fffu + ((u >> 16) & 1u)) >> 16;
  return (unsigned short)u;
}
__device__ __forceinline__ float bfh(unsigned short u) {
  return __uint_as_float(((unsigned int)u) << 16);
}

// ---------------- f32 -> bf16 convert ----------------
__global__ void convert_bf(const float* __restrict__ src, ushort* __restrict__ dst, int n) {
  int i = blockIdx.x * 256 + threadIdx.x;
  if (i < n) dst[i] = f2bf(src[i]);
}

// ---------------- part encoder ----------------
__global__ void part_encoder(const float* __restrict__ parts, const float* __restrict__ Wpe1,
                             const float* __restrict__ bpe1, const float* __restrict__ Wpe2,
                             const float* __restrict__ bpe2, const float* __restrict__ pos,
                             float* __restrict__ x, ushort* __restrict__ xb) {
  __shared__ float prow[16];
  __shared__ float pe1[128];
  int row = blockIdx.x;
  int s = row & 255;
  int tid = threadIdx.x;  // 128
  if (tid < 16) prow[tid] = parts[row * 16 + tid];
  __syncthreads();
  float a = bpe1[tid];
#pragma unroll
  for (int k = 0; k < 16; ++k) a = fmaf(prow[k], Wpe1[tid * 16 + k], a);
  pe1[tid] = fmaxf(a, 0.0f);
  __syncthreads();
  float a2 = bpe2[tid];
  for (int k = 0; k < 128; ++k) a2 = fmaf(pe1[k], Wpe2[tid * 128 + k], a2);
  x[(size_t)row * 256 + tid] = a2;
  xb[(size_t)row * 256 + tid] = f2bf(a2);
  if (tid < 64) {
    float p = pos[s * 64 + tid];
    x[(size_t)row * 256 + 128 + tid] = p;
    xb[(size_t)row * 256 + 128 + tid] = f2bf(p);
    x[(size_t)row * 256 + 192 + tid] = 0.0f;
    xb[(size_t)row * 256 + 192 + tid] = 0;
  }
}

// ---------------- MFMA bf16 GEMM ----------------
// OUT: 0 = f32 C[m][n]; 1 = bf16 C[m][n]; 2 = bf16 TRANSPOSED C[n*2056 + m]
template <int ACT, int OUT>
__global__ __launch_bounds__(256) void gemm_bf16(
    const ushort* __restrict__ A, const ushort* __restrict__ Wt,
    const float* __restrict__ bias1, const float* __restrict__ bias2,
    void* __restrict__ Cout, int N, int K) {
  int wid = threadIdx.x >> 6;
  int lane = threadIdx.x & 63;
  int m0 = blockIdx.y * 64 + wid * 16;
  int n0 = blockIdx.x * 64;
  int r15 = lane & 15;
  int kg = lane >> 4;
  f32x4 acc0 = {0.f, 0.f, 0.f, 0.f}, acc1 = acc0, acc2 = acc0, acc3 = acc0;
  const ushort* arow = A + (size_t)(m0 + r15) * K + kg * 8;
  const ushort* w0 = Wt + (size_t)(n0 + r15) * K + kg * 8;
  const ushort* w1 = w0 + (size_t)16 * K;
  const ushort* w2 = w0 + (size_t)32 * K;
  const ushort* w3 = w0 + (size_t)48 * K;
  for (int k0 = 0; k0 < K; k0 += 32) {
    bf16x8 af = *(const bf16x8*)(arow + k0);
    bf16x8 b0 = *(const bf16x8*)(w0 + k0);
    bf16x8 b1 = *(const bf16x8*)(w1 + k0);
    bf16x8 b2 = *(const bf16x8*)(w2 + k0);
    bf16x8 b3 = *(const bf16x8*)(w3 + k0);
    acc0 = __builtin_amdgcn_mfma_f32_16x16x32_bf16(af, b0, acc0, 0, 0, 0);
    acc1 = __builtin_amdgcn_mfma_f32_16x16x32_bf16(af, b1, acc1, 0, 0, 0);
    acc2 = __builtin_amdgcn_mfma_f32_16x16x32_bf16(af, b2, acc2, 0, 0, 0);
    acc3 = __builtin_amdgcn_mfma_f32_16x16x32_bf16(af, b3, acc3, 0, 0, 0);
  }
#pragma unroll
  for (int nn = 0; nn < 4; ++nn) {
    f32x4 a = (nn == 0) ? acc0 : (nn == 1) ? acc1 : (nn == 2) ? acc2 : acc3;
    int n = n0 + nn * 16 + r15;
    float bsum = bias1[n] + (bias2 ? bias2[n] : 0.0f);
    if (OUT == 2) {
      ushort4 s;
      float v0 = a[0] + bsum, v1 = a[1] + bsum, v2 = a[2] + bsum, v3 = a[3] + bsum;
      s.x = f2bf(v0); s.y = f2bf(v1); s.z = f2bf(v2); s.w = f2bf(v3);
      *(ushort4*)&((ushort*)Cout)[(size_t)n * 2056 + m0 + kg * 4] = s;
    } else {
#pragma unroll
      for (int r = 0; r < 4; ++r) {
        int m = m0 + kg * 4 + r;
        float v = a[r] + bsum;
        if (ACT == 1) v = fmaxf(v, 0.0f);
        if (OUT == 1)
          ((ushort*)Cout)[(size_t)m * N + n] = f2bf(v);
        else
          ((float*)Cout)[(size_t)m * N + n] = v;
      }
    }
  }
}

// ---------------- attention (f32 in, bf16 out) ----------------
__global__ void attn_kernel(const float* __restrict__ qkv, ushort* __restrict__ attout) {
  extern __shared__ float sm[];
  float* kl = sm;
  float* ql = sm + 256 * 33;
  float* sc = sm + 256 * 33 + 32 * 33;
  int qt = blockIdx.x, h = blockIdx.y, b = blockIdx.z;
  int tid = threadIdx.x;  // 256
  {
    int j = tid;
    const float* src = qkv + (size_t)(b * 256 + j) * 768 + 256 + h * 32;
#pragma unroll
    for (int d = 0; d < 32; d += 4) {
      float4 v = *(const float4*)(src + d);
      kl[j * 33 + d] = v.x; kl[j * 33 + d + 1] = v.y; kl[j * 33 + d + 2] = v.z; kl[j * 33 + d + 3] = v.w;
    }
  }
  {
    int i = tid >> 3, d4 = (tid & 7) * 4;
    const float* src = qkv + (size_t)(b * 256 + qt * 32 + i) * 768 + h * 32;
    float4 v = *(const float4*)(src + d4);
    ql[i * 33 + d4] = v.x; ql[i * 33 + d4 + 1] = v.y; ql[i * 33 + d4 + 2] = v.z; ql[i * 33 + d4 + 3] = v.w;
  }
  __syncthreads();
  int i = tid >> 3, c = tid & 7;
  const float scale = 0.17677669529663687f;
  float sv[32];
  float mx = -1e30f;
  for (int jj = 0; jj < 32; ++jj) {
    int j = jj * 8 + c;
    float s = 0.0f;
#pragma unroll
    for (int d = 0; d < 32; ++d) s = fmaf(ql[i * 33 + d], kl[j * 33 + d], s);
    s *= scale;
    sv[jj] = s;
    mx = fmaxf(mx, s);
  }
  mx = fmaxf(mx, __shfl_xor(mx, 1));
  mx = fmaxf(mx, __shfl_xor(mx, 2));
  mx = fmaxf(mx, __shfl_xor(mx, 4));
  float sum = 0.0f;
  for (int jj = 0; jj < 32; ++jj) {
    float p = __expf(sv[jj] - mx);
    sc[i * 257 + jj * 8 + c] = p;
    sum += p;
  }
  sum += __shfl_xor(sum, 1);
  sum += __shfl_xor(sum, 2);
  sum += __shfl_xor(sum, 4);
  float inv = 1.0f / sum;
  __syncthreads();
  float a0 = 0, a1 = 0, a2 = 0, a3 = 0;
  int d0 = c * 4;
  const float* vbase = qkv + 512 + h * 32 + d0;
  for (int j = 0; j < 256; ++j) {
    float p = sc[i * 257 + j];
    float4 v = *(const float4*)(vbase + (size_t)(b * 256 + j) * 768);
    a0 = fmaf(p, v.x, a0); a1 = fmaf(p, v.y, a1); a2 = fmaf(p, v.z, a2); a3 = fmaf(p, v.w, a3);
  }
  int orow = b * 256 + qt * 32 + i;
  ushort4 o4;
  o4.x = f2bf(a0 * inv); o4.y = f2bf(a1 * inv); o4.z = f2bf(a2 * inv); o4.w = f2bf(a3 * inv);
  *(ushort4*)&attout[(size_t)orow * 256 + h * 32 + d0] = o4;
}

// ---------------- LayerNorm(x + o) ----------------
__global__ void ln_residual(float* __restrict__ x, const float* __restrict__ o,
                            const float* __restrict__ g, const float* __restrict__ bt,
                            ushort* __restrict__ xb) {
  int row = blockIdx.x, tid = threadIdx.x;  // 256
  float e = x[(size_t)row * 256 + tid] + o[(size_t)row * 256 + tid];
  float s = e, q = e * e;
#pragma unroll
  for (int off = 32; off >= 1; off >>= 1) {
    s += __shfl_xor(s, off);
    q += __shfl_xor(q, off);
  }
  __shared__ float ps[4], pq[4];
  int wid = tid >> 6, lane = tid & 63;
  if (lane == 0) { ps[wid] = s; pq[wid] = q; }
  __syncthreads();
  float St = ps[0] + ps[1] + ps[2] + ps[3];
  float Qt = pq[0] + pq[1] + pq[2] + pq[3];
  float mean = St * (1.0f / 256.0f);
  float var = Qt * (1.0f / 256.0f) - mean * mean;
  float y = (e - mean) * rsqrtf(var + 1e-5f) * g[tid] + bt[tid];
  x[(size_t)row * 256 + tid] = y;
  xb[(size_t)row * 256 + tid] = f2bf(y);
}

// ---------------- gather dec_in ----------------
__global__ void gather_dec_in(const ushort* __restrict__ encb, const int* __restrict__ ts,
                              ushort* __restrict__ dec_in) {
  int bx = blockIdx.x;
  int t = bx >> 3, b = bx & 7;
  int tid = threadIdx.x;  // 64
  ushort4 v = {0, 0, 0, 0};
  if (t > 0) {
    int sidx = ts[b * 256 + t - 1];
    v = *(const ushort4*)&encb[((size_t)(b * 256 + sidx)) * 256 + tid * 4];
  }
  *(ushort4*)&dec_in[(size_t)bx * 256 + tid * 4] = v;
}

// ---------------- LSTM scan: MFMA, 1 block, 512 threads, all 8 batches --------
// Per step: G[16x1024] = H[16x256] @ Whh^T (rows 8..15 zero-padded).
// Wave w owns unit block U=[w*32,w*32+32): its 8 C-tiles nt=(gate g, half hf)
// cover cols g*256 + w*32 + hf*16 + (0..15)  ->  all 4 gates of U are wave-local.
// B-frags (m89 layout: col=lane&15, k-oct=lane>>4): tiles nt 0..5 in registers
// (48 frags = 192 regs, AGPR-backed), tiles 6,7 (g=3) from swizzled LDS (128 KB).
// H in LDS double-buffer [2][16][32]x16B, octet-XOR swizzled (o ^= row&7).
// Epilogue: shfl_xor(32) hands hf=1 gate sums to the padding-row lanes so all
// 64 lanes each do 4 (batch,unit) nonlinearity updates. One barrier per step.
__global__ __launch_bounds__(512) void lstm_scan(
    const ushort* __restrict__ XwT,   // [1024][2056] bf16, XwT[col][t*8+b]
    const ushort* __restrict__ Whb,   // [1024][256] bf16
    ushort* __restrict__ dec_out) {   // [8*256][256] bf16
  extern __shared__ char smem[];
  uint4* Bl = (uint4*)smem;               // [8][32][32] uint4 (128 KB)
  uint4* Hl = (uint4*)(smem + 131072);    // [2][16][32] uint4 (16 KB)
  int tid = threadIdx.x;
  int w = tid >> 6, l = tid & 63;
  int r15 = l & 15, kg = l >> 4;

  // fill B-LDS: cols 768 + bw*32 + lc (g=3 for every wave), octet-swizzled
  for (int i = 0; i < 16; ++i) {
    int idx = tid + i * 512;              // 0..8191
    int bw = idx >> 10, lc = (idx >> 5) & 31, oct = idx & 31;
    int col = 768 + bw * 32 + lc;
    Bl[bw * 1024 + lc * 32 + (oct ^ (lc & 7))] = ((const uint4*)Whb)[col * 32 + oct];
  }
  // zero both H buffers (rows 8..15 stay zero forever)
  uint4 z = {0, 0, 0, 0};
  Hl[tid] = z;
  Hl[tid + 512] = z;

  // register B-frags: tiles nt 0..5 (gates 0..2)
  bf16x8 fr[48];
#pragma unroll
  for (int nt = 0; nt < 6; ++nt) {
    int g = nt >> 1, hf = nt & 1;
    int col = g * 256 + w * 32 + hf * 16 + r15;
#pragma unroll
    for (int ks = 0; ks < 8; ++ks)
      fr[nt * 8 + ks] = ((const bf16x8*)Whb)[col * 32 + ks * 4 + kg];
  }
  float cst[4] = {0.f, 0.f, 0.f, 0.f};
  const int hfo = (kg >= 2) ? 1 : 0;
  const int b0 = (kg & 1) * 4;
  const int ucol = w * 32 + hfo * 16 + r15;
  const int lcb = r15;  // local col within LDS-B halves handled below
  __syncthreads();

  int cur = 0;
  for (int t = 0; t < 256; ++t) {
    f32x4 ac0 = {0.f, 0.f, 0.f, 0.f}, ac1 = ac0, ac2 = ac0, ac3 = ac0;
    f32x4 ac4 = ac0, ac5 = ac0, ac6 = ac0, ac7 = ac0;
    const uint4* hb = Hl + cur * 512;
#pragma unroll
    for (int half = 0; half < 2; ++half) {
      bf16x8 a0, a1, a2, a3;
      {
        int o0 = ((half * 4 + 0) * 4 + kg) ^ (r15 & 7);
        int o1 = ((half * 4 + 1) * 4 + kg) ^ (r15 & 7);
        int o2 = ((half * 4 + 2) * 4 + kg) ^ (r15 & 7);
        int o3 = ((half * 4 + 3) * 4 + kg) ^ (r15 & 7);
        a0 = ((const bf16x8*)hb)[r15 * 32 + o0];
        a1 = ((const bf16x8*)hb)[r15 * 32 + o1];
        a2 = ((const bf16x8*)hb)[r15 * 32 + o2];
        a3 = ((const bf16x8*)hb)[r15 * 32 + o3];
      }
#pragma unroll
      for (int j = 0; j < 4; ++j) {
        int ks = half * 4 + j;
        bf16x8 av = (j == 0) ? a0 : (j == 1) ? a1 : (j == 2) ? a2 : a3;
        // LDS B-frags for tiles 6,7 (gate 3)
        int lc6 = 0 * 16 + lcb, lc7 = 1 * 16 + lcb;
        bf16x8 b6 = ((const bf16x8*)Bl)[w * 1024 + lc6 * 32 + ((ks * 4 + kg) ^ (lc6 & 7))];
        bf16x8 b7 = ((const bf16x8*)Bl)[w * 1024 + lc7 * 32 + ((ks * 4 + kg) ^ (lc7 & 7))];
        ac0 = __builtin_amdgcn_mfma_f32_16x16x32_bf16(av, fr[0 * 8 + ks], ac0, 0, 0, 0);
        ac1 = __builtin_amdgcn_mfma_f32_16x16x32_bf16(av, fr[1 * 8 + ks], ac1, 0, 0, 0);
        ac2 = __builtin_amdgcn_mfma_f32_16x16x32_bf16(av, fr[2 * 8 + ks], ac2, 0, 0, 0);
        ac3 = __builtin_amdgcn_mfma_f32_16x16x32_bf16(av, fr[3 * 8 + ks], ac3, 0, 0, 0);
        ac4 = __builtin_amdgcn_mfma_f32_16x16x32_bf16(av, fr[4 * 8 + ks], ac4, 0, 0, 0);
        ac5 = __builtin_amdgcn_mfma_f32_16x16x32_bf16(av, fr[5 * 8 + ks], ac5, 0, 0, 0);
        ac6 = __builtin_amdgcn_mfma_f32_16x16x32_bf16(av, b6, ac6, 0, 0, 0);
        ac7 = __builtin_amdgcn_mfma_f32_16x16x32_bf16(av, b7, ac7, 0, 0, 0);
      }
    }
    // ---- epilogue: redistribute hf=1 gate sums to padding-row lanes ----
    float gv0[4], gv1[4], gv2[4], gv3[4];
#pragma unroll
    for (int r = 0; r < 4; ++r) {
      float s0 = __shfl_xor(ac1[r], 32);
      float s1 = __shfl_xor(ac3[r], 32);
      float s2 = __shfl_xor(ac5[r], 32);
      float s3 = __shfl_xor(ac7[r], 32);
      gv0[r] = hfo ? s0 : ac0[r];
      gv1[r] = hfo ? s1 : ac2[r];
      gv2[r] = hfo ? s2 : ac4[r];
      gv3[r] = hfo ? s3 : ac6[r];
    }
    int tb = t * 8 + b0;
    ushort4 x0 = *(const ushort4*)&XwT[(size_t)(0 * 256 + ucol) * 2056 + tb];
    ushort4 x1 = *(const ushort4*)&XwT[(size_t)(1 * 256 + ucol) * 2056 + tb];
    ushort4 x2 = *(const ushort4*)&XwT[(size_t)(2 * 256 + ucol) * 2056 + tb];
    ushort4 x3 = *(const ushort4*)&XwT[(size_t)(3 * 256 + ucol) * 2056 + tb];
    const ushort* px0 = (const ushort*)&x0;
    const ushort* px1 = (const ushort*)&x1;
    const ushort* px2 = (const ushort*)&x2;
    const ushort* px3 = (const ushort*)&x3;
    ushort* hn = (ushort*)(Hl + (cur ^ 1) * 512);
#pragma unroll
    for (int r = 0; r < 4; ++r) {
      float gi = gv0[r] + bfh(px0[r]);
      float gf = gv1[r] + bfh(px1[r]);
      float gg = gv2[r] + bfh(px2[r]);
      float go = gv3[r] + bfh(px3[r]);
      float cn = sigf(gf) * cst[r] + sigf(gi) * tanhfast(gg);
      cst[r] = cn;
      float hv = sigf(go) * tanhfast(cn);
      int row = b0 + r;
      hn[row * 256 + (((ucol >> 3) ^ (row & 7)) * 8) + (ucol & 7)] = f2bf(hv);
      dec_out[((size_t)(row * 256 + t)) * 256 + ucol] = f2bf(hv);
    }
    __syncthreads();
    cur ^= 1;
  }
}

// ---------------- pen transpose ----------------
__global__ void transpose_pen(const float* __restrict__ pen, float* __restrict__ penT) {
  int bx = blockIdx.x;
  int b = bx >> 8, h = bx & 255;
  int i = threadIdx.x;  // 256
  penT[(size_t)bx * 256 + i] = pen[((size_t)(b * 256 + i)) * 256 + h];
}

// ---------------- pointer logits ----------------
__global__ void pointer_kernel(const float* __restrict__ pd, const float* __restrict__ penT,
                               const float* __restrict__ vptr, float* __restrict__ out) {
  __shared__ float pdr[256];
  __shared__ float vl[256];
  int bx = blockIdx.x;
  int b = bx >> 8;
  int tid = threadIdx.x;  // 256
  pdr[tid] = pd[(size_t)bx * 256 + tid];
  vl[tid] = vptr[tid];
  __syncthreads();
  const float* pT = penT + (size_t)b * 256 * 256;
  float acc = 0.0f;
  for (int h = 0; h < 256; ++h) {
    acc = fmaf(vl[h], tanhfast(pdr[h] + pT[(size_t)h * 256 + tid]), acc);
  }
  out[(size_t)bx * 256 + tid] = acc;
}

extern "C" void kernel_launch(void* const* d_in, const int* in_sizes, int n_in,
                              void* d_out, int out_size, void* d_ws, size_t ws_size,
                              hipStream_t stream) {
  const float* parts = (const float*)d_in[0];
  const int* ts = (const int*)d_in[1];
  const float* Wpe1 = (const float*)d_in[2];
  const float* bpe1 = (const float*)d_in[3];
  const float* Wpe2 = (const float*)d_in[4];
  const float* bpe2 = (const float*)d_in[5];
  const float* pos = (const float*)d_in[6];
  const float* Wqkv = (const float*)d_in[7];
  const float* bqkv = (const float*)d_in[8];
  const float* Wo = (const float*)d_in[9];
  const float* bo = (const float*)d_in[10];
  const float* ln1g = (const float*)d_in[11];
  const float* ln1b = (const float*)d_in[12];
  const float* W1f = (const float*)d_in[13];
  const float* b1f = (const float*)d_in[14];
  const float* W2f = (const float*)d_in[15];
  const float* b2f = (const float*)d_in[16];
  const float* ln2g = (const float*)d_in[17];
  const float* ln2b = (const float*)d_in[18];
  const float* Wih = (const float*)d_in[19];
  const float* Whh = (const float*)d_in[20];
  const float* bih = (const float*)d_in[21];
  const float* bhh = (const float*)d_in[22];
  const float* Wp = (const float*)d_in[23];
  const float* bp = (const float*)d_in[24];
  const float* vptr = (const float*)d_in[25];
  float* out = (float*)d_out;

  // ---- workspace layout (f32-slot units); end = 4751360 slots = 19 MB ----
  float* W = (float*)d_ws;
  float* xbuf = W;                            // [2048,256] f32, live all
  ushort* xbf = (ushort*)(W + 524288);        // [2048,256] bf16, live all
  float* SCR = W + 786432;                    // 2097152 slots scratch
  float* qkvb = SCR;                          //   encoder: [2048,768] f32
  float* obuf = SCR + 1572864;                //   encoder: [2048,256] f32
  ushort* XwT = (ushort*)SCR;                 //   decoder: [1024][2056] bf16 (1052672 slots)
  float* pdb = SCR;                           //   tail: [2048,256] f32
  float* penb = SCR + 524288;                 //   tail: [2048,256] f32
  float* penTb = SCR + 1048576;               //   tail: [2048,256] f32
  ushort* attbf = (ushort*)(W + 2883584);     // [2048,256] bf16 (encoder)
  ushort* ffbf = (ushort*)(W + 3145728);      // [2048,512] bf16 (encoder)
  ushort* dec_inbf = (ushort*)(W + 3145728);  //   decoder: [2048,256] bf16
  ushort* dec_outbf = (ushort*)(W + 3407872); //   decoder: [2048,256] bf16
  ushort* wqkvbf = (ushort*)(W + 3670016);    // 589824 bf16
  ushort* wobf   = (ushort*)(W + 3964928);    // 196608
  ushort* w1fbf  = (ushort*)(W + 4063232);    // 393216
  ushort* w2fbf  = (ushort*)(W + 4259840);    // 393216
  ushort* wihbf  = (ushort*)(W + 4456448);    // 262144
  ushort* wpbf   = (ushort*)(W + 4587520);    // 65536
  ushort* whhbf  = (ushort*)(W + 4620288);    // 262144

  const int attnLDS = (256 * 33 + 32 * 33 + 32 * 257) * 4;  // 70912 B
  const int scanLDS = 131072 + 16384;                       // 147456 B
  hipFuncSetAttribute((const void*)attn_kernel, hipFuncAttributeMaxDynamicSharedMemorySize, attnLDS);
  hipFuncSetAttribute((const void*)lstm_scan, hipFuncAttributeMaxDynamicSharedMemorySize, scanLDS);

  // weight conversions
  convert_bf<<<(589824 + 255) / 256, 256, 0, stream>>>(Wqkv, wqkvbf, 589824);
  convert_bf<<<(196608 + 255) / 256, 256, 0, stream>>>(Wo, wobf, 196608);
  convert_bf<<<(393216 + 255) / 256, 256, 0, stream>>>(W1f, w1fbf, 393216);
  convert_bf<<<(393216 + 255) / 256, 256, 0, stream>>>(W2f, w2fbf, 393216);
  convert_bf<<<(262144 + 255) / 256, 256, 0, stream>>>(Wih, wihbf, 262144);
  convert_bf<<<(65536 + 255) / 256, 256, 0, stream>>>(Wp, wpbf, 65536);
  convert_bf<<<(262144 + 255) / 256, 256, 0, stream>>>(Whh, whhbf, 262144);

  part_encoder<<<2048, 128, 0, stream>>>(parts, Wpe1, bpe1, Wpe2, bpe2, pos, xbuf, xbf);
  for (int l = 0; l < 3; ++l) {
    gemm_bf16<0, 0><<<dim3(12, 32), 256, 0, stream>>>(xbf, wqkvbf + (size_t)l * 196608,
                                                      bqkv + l * 768, nullptr, qkvb, 768, 256);
    attn_kernel<<<dim3(8, 8, 8), 256, attnLDS, stream>>>(qkvb, attbf);
    gemm_bf16<0, 0><<<dim3(4, 32), 256, 0, stream>>>(attbf, wobf + (size_t)l * 65536,
                                                     bo + l * 256, nullptr, obuf, 256, 256);
    ln_residual<<<2048, 256, 0, stream>>>(xbuf, obuf, ln1g + l * 256, ln1b + l * 256, xbf);
    gemm_bf16<1, 1><<<dim3(8, 32), 256, 0, stream>>>(xbf, w1fbf + (size_t)l * 131072,
                                                     b1f + l * 512, nullptr, ffbf, 512, 256);
    gemm_bf16<0, 0><<<dim3(4, 32), 256, 0, stream>>>(ffbf, w2fbf + (size_t)l * 131072,
                                                     b2f + l * 256, nullptr, obuf, 256, 512);
    ln_residual<<<2048, 256, 0, stream>>>(xbuf, obuf, ln2g + l * 256, ln2b + l * 256, xbf);
  }
  gather_dec_in<<<2048, 64, 0, stream>>>(xbf, ts, dec_inbf);
  // Xw = dec_in @ Wih^T + bih + bhh, written bf16-TRANSPOSED: XwT[col][t*8+b]
  gemm_bf16<0, 2><<<dim3(16, 32), 256, 0, stream>>>(dec_inbf, wihbf, bih, bhh, XwT, 1024, 256);
  lstm_scan<<<1, 512, scanLDS, stream>>>(XwT, whhbf, dec_outbf);
  gemm_bf16<0, 0><<<dim3(4, 32), 256, 0, stream>>>(dec_outbf, wpbf, bp, nullptr, pdb, 256, 256);
  gemm_bf16<0, 0><<<dim3(4, 32), 256, 0, stream>>>(xbf, wpbf, bp, nullptr, penb, 256, 256);
  transpose_pen<<<2048, 256, 0, stream>>>(penb, penTb);
  pointer_kernel<<<2048, 256, 0, stream>>>(pdb, penTb, vptr, out);
}

// Round 8
// 1158.372 us; speedup vs baseline: 1.2982x; 1.2982x over previous
//
#include <hip/hip_runtime.h>
#include <cstdint>
#include <cstddef>

typedef _Float16 h2 __attribute__((ext_vector_type(2)));
typedef short bf16x8 __attribute__((ext_vector_type(8)));
typedef float f32x4 __attribute__((ext_vector_type(4)));

__device__ __forceinline__ float sigf(float x) { return 1.0f / (1.0f + __expf(-x)); }
__device__ __forceinline__ float tanhfast(float x) {
  float e = __expf(-2.0f * fabsf(x));
  float t = (1.0f - e) / (1.0f + e);
  return copysignf(t, x);
}
__device__ __forceinline__ h2 cvt2(float a, float b) {
  h2 r; r.x = (_Float16)a; r.y = (_Float16)b; return r;
}
__device__ __forceinline__ h2 bch2(unsigned int u) { return __builtin_bit_cast(h2, u); }
__device__ __forceinline__ unsigned short f2bf(float f) {
  unsigned int u = __float_as_uint(f);
  u = (u + 0x7fffu + ((u >> 16) & 1u)) >> 16;
  return (unsigned short)u;
}

__device__ __forceinline__ float fdot2f(h2 a, h2 b, float c) {
#if __has_builtin(__builtin_amdgcn_fdot2)
  return __builtin_amdgcn_fdot2(a, b, c, false);
#else
  return fmaf((float)a.x, (float)b.x, fmaf((float)a.y, (float)b.y, c));
#endif
}

// ---------------- f32 -> bf16 convert ----------------
__global__ void convert_bf(const float* __restrict__ src, ushort* __restrict__ dst, int n) {
  int i = blockIdx.x * 256 + threadIdx.x;
  if (i < n) dst[i] = f2bf(src[i]);
}

// ---------------- part encoder ----------------
__global__ void part_encoder(const float* __restrict__ parts, const float* __restrict__ Wpe1,
                             const float* __restrict__ bpe1, const float* __restrict__ Wpe2,
                             const float* __restrict__ bpe2, const float* __restrict__ pos,
                             float* __restrict__ x, ushort* __restrict__ xb) {
  __shared__ float prow[16];
  __shared__ float pe1[128];
  int row = blockIdx.x;
  int s = row & 255;
  int tid = threadIdx.x;  // 128
  if (tid < 16) prow[tid] = parts[row * 16 + tid];
  __syncthreads();
  float a = bpe1[tid];
#pragma unroll
  for (int k = 0; k < 16; ++k) a = fmaf(prow[k], Wpe1[tid * 16 + k], a);
  pe1[tid] = fmaxf(a, 0.0f);
  __syncthreads();
  float a2 = bpe2[tid];
  for (int k = 0; k < 128; ++k) a2 = fmaf(pe1[k], Wpe2[tid * 128 + k], a2);
  x[(size_t)row * 256 + tid] = a2;
  xb[(size_t)row * 256 + tid] = f2bf(a2);
  if (tid < 64) {
    float p = pos[s * 64 + tid];
    x[(size_t)row * 256 + 128 + tid] = p;
    xb[(size_t)row * 256 + 128 + tid] = f2bf(p);
    x[(size_t)row * 256 + 192 + tid] = 0.0f;
    xb[(size_t)row * 256 + 192 + tid] = 0;
  }
}

// ---------------- MFMA bf16 GEMM ----------------
// OUT: 0 = f32 C[m][n]; 1 = bf16 C[m][n]
template <int ACT, int OUT>
__global__ __launch_bounds__(256) void gemm_bf16(
    const ushort* __restrict__ A, const ushort* __restrict__ Wt,
    const float* __restrict__ bias1, const float* __restrict__ bias2,
    void* __restrict__ Cout, int N, int K) {
  int wid = threadIdx.x >> 6;
  int lane = threadIdx.x & 63;
  int m0 = blockIdx.y * 64 + wid * 16;
  int n0 = blockIdx.x * 64;
  int r15 = lane & 15;
  int kg = lane >> 4;
  f32x4 acc0 = {0.f, 0.f, 0.f, 0.f}, acc1 = acc0, acc2 = acc0, acc3 = acc0;
  const ushort* arow = A + (size_t)(m0 + r15) * K + kg * 8;
  const ushort* w0 = Wt + (size_t)(n0 + r15) * K + kg * 8;
  const ushort* w1 = w0 + (size_t)16 * K;
  const ushort* w2 = w0 + (size_t)32 * K;
  const ushort* w3 = w0 + (size_t)48 * K;
  for (int k0 = 0; k0 < K; k0 += 32) {
    bf16x8 af = *(const bf16x8*)(arow + k0);
    bf16x8 b0 = *(const bf16x8*)(w0 + k0);
    bf16x8 b1 = *(const bf16x8*)(w1 + k0);
    bf16x8 b2 = *(const bf16x8*)(w2 + k0);
    bf16x8 b3 = *(const bf16x8*)(w3 + k0);
    acc0 = __builtin_amdgcn_mfma_f32_16x16x32_bf16(af, b0, acc0, 0, 0, 0);
    acc1 = __builtin_amdgcn_mfma_f32_16x16x32_bf16(af, b1, acc1, 0, 0, 0);
    acc2 = __builtin_amdgcn_mfma_f32_16x16x32_bf16(af, b2, acc2, 0, 0, 0);
    acc3 = __builtin_amdgcn_mfma_f32_16x16x32_bf16(af, b3, acc3, 0, 0, 0);
  }
#pragma unroll
  for (int nn = 0; nn < 4; ++nn) {
    f32x4 a = (nn == 0) ? acc0 : (nn == 1) ? acc1 : (nn == 2) ? acc2 : acc3;
    int n = n0 + nn * 16 + r15;
    float bsum = bias1[n] + (bias2 ? bias2[n] : 0.0f);
#pragma unroll
    for (int r = 0; r < 4; ++r) {
      int m = m0 + kg * 4 + r;
      float v = a[r] + bsum;
      if (ACT == 1) v = fmaxf(v, 0.0f);
      if (OUT == 1)
        ((ushort*)Cout)[(size_t)m * N + n] = f2bf(v);
      else
        ((float*)Cout)[(size_t)m * N + n] = v;
    }
  }
}

// ---------------- attention (f32 in, bf16 out) ----------------
__global__ void attn_kernel(const float* __restrict__ qkv, ushort* __restrict__ attout) {
  extern __shared__ float sm[];
  float* kl = sm;
  float* ql = sm + 256 * 33;
  float* sc = sm + 256 * 33 + 32 * 33;
  int qt = blockIdx.x, h = blockIdx.y, b = blockIdx.z;
  int tid = threadIdx.x;  // 256
  {
    int j = tid;
    const float* src = qkv + (size_t)(b * 256 + j) * 768 + 256 + h * 32;
#pragma unroll
    for (int d = 0; d < 32; d += 4) {
      float4 v = *(const float4*)(src + d);
      kl[j * 33 + d] = v.x; kl[j * 33 + d + 1] = v.y; kl[j * 33 + d + 2] = v.z; kl[j * 33 + d + 3] = v.w;
    }
  }
  {
    int i = tid >> 3, d4 = (tid & 7) * 4;
    const float* src = qkv + (size_t)(b * 256 + qt * 32 + i) * 768 + h * 32;
    float4 v = *(const float4*)(src + d4);
    ql[i * 33 + d4] = v.x; ql[i * 33 + d4 + 1] = v.y; ql[i * 33 + d4 + 2] = v.z; ql[i * 33 + d4 + 3] = v.w;
  }
  __syncthreads();
  int i = tid >> 3, c = tid & 7;
  const float scale = 0.17677669529663687f;
  float sv[32];
  float mx = -1e30f;
  for (int jj = 0; jj < 32; ++jj) {
    int j = jj * 8 + c;
    float s = 0.0f;
#pragma unroll
    for (int d = 0; d < 32; ++d) s = fmaf(ql[i * 33 + d], kl[j * 33 + d], s);
    s *= scale;
    sv[jj] = s;
    mx = fmaxf(mx, s);
  }
  mx = fmaxf(mx, __shfl_xor(mx, 1));
  mx = fmaxf(mx, __shfl_xor(mx, 2));
  mx = fmaxf(mx, __shfl_xor(mx, 4));
  float sum = 0.0f;
  for (int jj = 0; jj < 32; ++jj) {
    float p = __expf(sv[jj] - mx);
    sc[i * 257 + jj * 8 + c] = p;
    sum += p;
  }
  sum += __shfl_xor(sum, 1);
  sum += __shfl_xor(sum, 2);
  sum += __shfl_xor(sum, 4);
  float inv = 1.0f / sum;
  __syncthreads();
  float a0 = 0, a1 = 0, a2 = 0, a3 = 0;
  int d0 = c * 4;
  const float* vbase = qkv + 512 + h * 32 + d0;
  for (int j = 0; j < 256; ++j) {
    float p = sc[i * 257 + j];
    float4 v = *(const float4*)(vbase + (size_t)(b * 256 + j) * 768);
    a0 = fmaf(p, v.x, a0); a1 = fmaf(p, v.y, a1); a2 = fmaf(p, v.z, a2); a3 = fmaf(p, v.w, a3);
  }
  int orow = b * 256 + qt * 32 + i;
  ushort4 o4;
  o4.x = f2bf(a0 * inv); o4.y = f2bf(a1 * inv); o4.z = f2bf(a2 * inv); o4.w = f2bf(a3 * inv);
  *(ushort4*)&attout[(size_t)orow * 256 + h * 32 + d0] = o4;
}

// ---------------- LayerNorm(x + o) ----------------
__global__ void ln_residual(float* __restrict__ x, const float* __restrict__ o,
                            const float* __restrict__ g, const float* __restrict__ bt,
                            ushort* __restrict__ xb) {
  int row = blockIdx.x, tid = threadIdx.x;  // 256
  float e = x[(size_t)row * 256 + tid] + o[(size_t)row * 256 + tid];
  float s = e, q = e * e;
#pragma unroll
  for (int off = 32; off >= 1; off >>= 1) {
    s += __shfl_xor(s, off);
    q += __shfl_xor(q, off);
  }
  __shared__ float ps[4], pq[4];
  int wid = tid >> 6, lane = tid & 63;
  if (lane == 0) { ps[wid] = s; pq[wid] = q; }
  __syncthreads();
  float St = ps[0] + ps[1] + ps[2] + ps[3];
  float Qt = pq[0] + pq[1] + pq[2] + pq[3];
  float mean = St * (1.0f / 256.0f);
  float var = Qt * (1.0f / 256.0f) - mean * mean;
  float y = (e - mean) * rsqrtf(var + 1e-5f) * g[tid] + bt[tid];
  x[(size_t)row * 256 + tid] = y;
  xb[(size_t)row * 256 + tid] = f2bf(y);
}

// ---------------- gather dec_in ----------------
__global__ void gather_dec_in(const ushort* __restrict__ encb, const int* __restrict__ ts,
                              ushort* __restrict__ dec_in) {
  int bx = blockIdx.x;
  int t = bx >> 3, b = bx & 7;
  int tid = threadIdx.x;  // 64
  ushort4 v = {0, 0, 0, 0};
  if (t > 0) {
    int sidx = ts[b * 256 + t - 1];
    v = *(const ushort4*)&encb[((size_t)(b * 256 + sidx)) * 256 + tid * 4];
  }
  *(ushort4*)&dec_in[(size_t)bx * 256 + tid * 4] = v;
}

// ---------------- LSTM scan: 4 CUs per batch, weights fully register-resident --
// 32 blocks, bx = s4*8 + b: the 4 partner blocks of batch b land on the SAME XCD
// (round-robin bx%8, m09). Block owns units [s4*64, s4*64+64), all 4 gates.
// Thread tid = ul*4 + g owns gate-row R = g*256 + s4*64 + ul: 256 cols f16
// = 128 h2 VGPRs (need ~170 total; 256-thread + waves_per_eu(1,1) is the ONLY
// config granted 256 arch VGPRs -- R3/R5/R6/R7 evidence). Zero LDS weights,
// zero streaming. Quad (lanes 4u..4u+3) holds (i,f,g,o); 4 __shfl assemble all
// gates in all 4 lanes; c,h computed redundantly.
// Cross-CU h-exchange per step: relaxed agent-scope atomic u32 stores (data at
// coherence point; no fences/wbl2), flag = relaxed fetch_add after
// __syncthreads (vmcnt(0) drain orders data before flag), readers poll acquire
// then relaxed-load. NO __threadfence (R1's 6us/step killer).
__global__ __attribute__((amdgpu_flat_work_group_size(256, 256), amdgpu_waves_per_eu(1, 1)))
void lstm_scan(const float* __restrict__ Xw, const float* __restrict__ Whh,
               ushort* __restrict__ dec_out, unsigned int* __restrict__ hg,
               unsigned int* __restrict__ flags) {
  __shared__ _Float16 hbuf[2][256];
  int bx = blockIdx.x;
  int s4 = bx >> 3, b = bx & 7;
  int tid = threadIdx.x;       // 0..255
  int ul = tid >> 2, g = tid & 3;
  int gu = s4 * 64 + ul;       // global unit
  int R = g * 256 + gu;        // gate row (i,f,g,o blocks of 256)

  h2 w[128];
  {
    const float4* src = (const float4*)(Whh + (size_t)R * 256);
#pragma unroll
    for (int k = 0; k < 64; ++k) {
      float4 v = src[k];
      w[2 * k] = cvt2(v.x, v.y);
      w[2 * k + 1] = cvt2(v.z, v.w);
    }
  }
  hbuf[0][tid] = (_Float16)0.0f;
  float c = 0.0f;
  float xnext = Xw[(size_t)b * 1024 + R];
  unsigned int* myflag = &flags[bx];
  int lw = tid & 63, qbase = lw & ~3;
  __syncthreads();

  int cur = 0;
  for (int t = 0; t < 256; ++t) {
    float xcur = xnext;
    if (t < 255) xnext = Xw[(size_t)((t + 1) * 8 + b) * 1024 + R];
    const uint4* hb = (const uint4*)hbuf[cur];
    float a0 = 0.f, a1 = 0.f, a2 = 0.f, a3 = 0.f;
#pragma unroll
    for (int q = 0; q < 32; ++q) {
      uint4 hv = hb[q];
      a0 = fdot2f(w[4 * q + 0], bch2(hv.x), a0);
      a1 = fdot2f(w[4 * q + 1], bch2(hv.y), a1);
      a2 = fdot2f(w[4 * q + 2], bch2(hv.z), a2);
      a3 = fdot2f(w[4 * q + 3], bch2(hv.w), a3);
    }
    float gsum = (a0 + a1) + (a2 + a3) + xcur;
    // quad assembly: lane qbase+k holds gate k sum
    float gi = __shfl(gsum, qbase + 0);
    float gf = __shfl(gsum, qbase + 1);
    float gg = __shfl(gsum, qbase + 2);
    float go = __shfl(gsum, qbase + 3);
    c = sigf(gf) * c + sigf(gi) * tanhfast(gg);
    float hv_ = sigf(go) * tanhfast(c);
    _Float16 hf = (_Float16)hv_;
    if (g == 0) hbuf[cur ^ 1][gu] = hf;
    if (g == 1 && t < 255) {
      __hip_atomic_store(&hg[(size_t)((t + 1) & 1) * 2048 + b * 256 + gu],
                         (unsigned int)__builtin_bit_cast(unsigned short, hf),
                         __ATOMIC_RELAXED, __HIP_MEMORY_SCOPE_AGENT);
    }
    if (g == 2) dec_out[((size_t)(b * 256 + t)) * 256 + gu] = f2bf(hv_);
    if (t < 255) {
      __syncthreads();  // drains vmcnt(0): data atomics globally visible
      if (tid == 0)
        __hip_atomic_fetch_add(myflag, 1u, __ATOMIC_RELAXED, __HIP_MEMORY_SCOPE_AGENT);
      if (tid < 192) {
        int pi = tid >> 6;
        int p = pi + (pi >= s4 ? 1 : 0);      // partner block index (no array: rule #20)
        unsigned int* pf = &flags[p * 8 + b];
        while (__hip_atomic_load(pf, __ATOMIC_ACQUIRE, __HIP_MEMORY_SCOPE_AGENT) <= (unsigned)t)
          __builtin_amdgcn_s_sleep(1);
        int u2 = tid & 63;
        unsigned int v = __hip_atomic_load(
            &hg[(size_t)((t + 1) & 1) * 2048 + b * 256 + p * 64 + u2],
            __ATOMIC_RELAXED, __HIP_MEMORY_SCOPE_AGENT);
        hbuf[cur ^ 1][p * 64 + u2] = __builtin_bit_cast(_Float16, (unsigned short)v);
      }
      __syncthreads();
    }
    cur ^= 1;
  }
}

// ---------------- pen transpose ----------------
__global__ void transpose_pen(const float* __restrict__ pen, float* __restrict__ penT) {
  int bx = blockIdx.x;
  int b = bx >> 8, h = bx & 255;
  int i = threadIdx.x;  // 256
  penT[(size_t)bx * 256 + i] = pen[((size_t)(b * 256 + i)) * 256 + h];
}

// ---------------- pointer logits ----------------
__global__ void pointer_kernel(const float* __restrict__ pd, const float* __restrict__ penT,
                               const float* __restrict__ vptr, float* __restrict__ out) {
  __shared__ float pdr[256];
  __shared__ float vl[256];
  int bx = blockIdx.x;
  int b = bx >> 8;
  int tid = threadIdx.x;  // 256
  pdr[tid] = pd[(size_t)bx * 256 + tid];
  vl[tid] = vptr[tid];
  __syncthreads();
  const float* pT = penT + (size_t)b * 256 * 256;
  float acc = 0.0f;
  for (int h = 0; h < 256; ++h) {
    acc = fmaf(vl[h], tanhfast(pdr[h] + pT[(size_t)h * 256 + tid]), acc);
  }
  out[(size_t)bx * 256 + tid] = acc;
}

extern "C" void kernel_launch(void* const* d_in, const int* in_sizes, int n_in,
                              void* d_out, int out_size, void* d_ws, size_t ws_size,
                              hipStream_t stream) {
  const float* parts = (const float*)d_in[0];
  const int* ts = (const int*)d_in[1];
  const float* Wpe1 = (const float*)d_in[2];
  const float* bpe1 = (const float*)d_in[3];
  const float* Wpe2 = (const float*)d_in[4];
  const float* bpe2 = (const float*)d_in[5];
  const float* pos = (const float*)d_in[6];
  const float* Wqkv = (const float*)d_in[7];
  const float* bqkv = (const float*)d_in[8];
  const float* Wo = (const float*)d_in[9];
  const float* bo = (const float*)d_in[10];
  const float* ln1g = (const float*)d_in[11];
  const float* ln1b = (const float*)d_in[12];
  const float* W1f = (const float*)d_in[13];
  const float* b1f = (const float*)d_in[14];
  const float* W2f = (const float*)d_in[15];
  const float* b2f = (const float*)d_in[16];
  const float* ln2g = (const float*)d_in[17];
  const float* ln2b = (const float*)d_in[18];
  const float* Wih = (const float*)d_in[19];
  const float* Whh = (const float*)d_in[20];
  const float* bih = (const float*)d_in[21];
  const float* bhh = (const float*)d_in[22];
  const float* Wp = (const float*)d_in[23];
  const float* bp = (const float*)d_in[24];
  const float* vptr = (const float*)d_in[25];
  float* out = (float*)d_out;

  // ---- workspace layout (f32-slot units) ----
  float* W = (float*)d_ws;
  float* xbuf = W;                            // [2048,256] f32, live all
  ushort* xbf = (ushort*)(W + 524288);        // [2048,256] bf16, live all
  float* SCR = W + 786432;                    // 2097152 slots scratch
  float* qkvb = SCR;                          //   encoder: [2048,768] f32
  float* obuf = SCR + 1572864;                //   encoder: [2048,256] f32
  float* Xw = SCR;                            //   decoder: [2048,1024] f32
  float* pdb = SCR;                           //   tail: [2048,256] f32
  float* penb = SCR + 524288;                 //   tail: [2048,256] f32
  float* penTb = SCR + 1048576;               //   tail: [2048,256] f32
  ushort* attbf = (ushort*)(W + 2883584);     // [2048,256] bf16 (encoder)
  ushort* ffbf = (ushort*)(W + 3145728);      // [2048,512] bf16 (encoder)
  ushort* dec_inbf = (ushort*)(W + 3145728);  //   decoder: [2048,256] bf16
  ushort* dec_outbf = (ushort*)(W + 3407872); //   decoder: [2048,256] bf16
  ushort* wqkvbf = (ushort*)(W + 3670016);    // 589824 bf16
  ushort* wobf   = (ushort*)(W + 3964928);    // 196608
  ushort* w1fbf  = (ushort*)(W + 4063232);    // 393216
  ushort* w2fbf  = (ushort*)(W + 4259840);    // 393216
  ushort* wihbf  = (ushort*)(W + 4456448);    // 262144
  ushort* wpbf   = (ushort*)(W + 4587520);    // 65536
  unsigned int* hg = (unsigned int*)(W + 4620288);     // [2][8][256] u32 (16 KB)
  unsigned int* flags = (unsigned int*)(W + 4624384);  // [32] u32

  const int attnLDS = (256 * 33 + 32 * 33 + 32 * 257) * 4;  // 70912 B
  hipFuncSetAttribute((const void*)attn_kernel, hipFuncAttributeMaxDynamicSharedMemorySize, attnLDS);

  // weight conversions
  convert_bf<<<(589824 + 255) / 256, 256, 0, stream>>>(Wqkv, wqkvbf, 589824);
  convert_bf<<<(196608 + 255) / 256, 256, 0, stream>>>(Wo, wobf, 196608);
  convert_bf<<<(393216 + 255) / 256, 256, 0, stream>>>(W1f, w1fbf, 393216);
  convert_bf<<<(393216 + 255) / 256, 256, 0, stream>>>(W2f, w2fbf, 393216);
  convert_bf<<<(262144 + 255) / 256, 256, 0, stream>>>(Wih, wihbf, 262144);
  convert_bf<<<(65536 + 255) / 256, 256, 0, stream>>>(Wp, wpbf, 65536);

  part_encoder<<<2048, 128, 0, stream>>>(parts, Wpe1, bpe1, Wpe2, bpe2, pos, xbuf, xbf);
  for (int l = 0; l < 3; ++l) {
    gemm_bf16<0, 0><<<dim3(12, 32), 256, 0, stream>>>(xbf, wqkvbf + (size_t)l * 196608,
                                                      bqkv + l * 768, nullptr, qkvb, 768, 256);
    attn_kernel<<<dim3(8, 8, 8), 256, attnLDS, stream>>>(qkvb, attbf);
    gemm_bf16<0, 0><<<dim3(4, 32), 256, 0, stream>>>(attbf, wobf + (size_t)l * 65536,
                                                     bo + l * 256, nullptr, obuf, 256, 256);
    ln_residual<<<2048, 256, 0, stream>>>(xbuf, obuf, ln1g + l * 256, ln1b + l * 256, xbf);
    gemm_bf16<1, 1><<<dim3(8, 32), 256, 0, stream>>>(xbf, w1fbf + (size_t)l * 131072,
                                                     b1f + l * 512, nullptr, ffbf, 512, 256);
    gemm_bf16<0, 0><<<dim3(4, 32), 256, 0, stream>>>(ffbf, w2fbf + (size_t)l * 131072,
                                                     b2f + l * 256, nullptr, obuf, 256, 512);
    ln_residual<<<2048, 256, 0, stream>>>(xbuf, obuf, ln2g + l * 256, ln2b + l * 256, xbf);
  }
  gather_dec_in<<<2048, 64, 0, stream>>>(xbf, ts, dec_inbf);
  gemm_bf16<0, 0><<<dim3(16, 32), 256, 0, stream>>>(dec_inbf, wihbf, bih, bhh, Xw, 1024, 256);
  hipMemsetAsync(flags, 0, 32 * sizeof(unsigned int), stream);
  lstm_scan<<<32, 256, 0, stream>>>(Xw, Whh, dec_outbf, hg, flags);
  gemm_bf16<0, 0><<<dim3(4, 32), 256, 0, stream>>>(dec_outbf, wpbf, bp, nullptr, pdb, 256, 256);
  gemm_bf16<0, 0><<<dim3(4, 32), 256, 0, stream>>>(xbf, wpbf, bp, nullptr, penb, 256, 256);
  transpose_pen<<<2048, 256, 0, stream>>>(penb, penTb);
  pointer_kernel<<<2048, 256, 0, stream>>>(pdb, penTb, vptr, out);
}

// Round 10
// 1032.546 us; speedup vs baseline: 1.4563x; 1.1219x over previous
//
#include <hip/hip_runtime.h>
#include <cstdint>
#include <cstddef>

typedef _Float16 h2 __attribute__((ext_vector_type(2)));
typedef short bf16x8 __attribute__((ext_vector_type(8)));
typedef float f32x4 __attribute__((ext_vector_type(4)));

__device__ __forceinline__ float sigf(float x) { return 1.0f / (1.0f + __expf(-x)); }
__device__ __forceinline__ float tanhfast(float x) {
  float e = __expf(-2.0f * fabsf(x));
  float t = (1.0f - e) / (1.0f + e);
  return copysignf(t, x);
}
__device__ __forceinline__ h2 cvt2(float a, float b) {
  h2 r; r.x = (_Float16)a; r.y = (_Float16)b; return r;
}
__device__ __forceinline__ h2 bch2(unsigned int u) { return __builtin_bit_cast(h2, u); }
__device__ __forceinline__ unsigned int bcu(h2 v) { return __builtin_bit_cast(unsigned int, v); }
__device__ __forceinline__ unsigned short f2bf(float f) {
  unsigned int u = __float_as_uint(f);
  u = (u + 0x7fffu + ((u >> 16) & 1u)) >> 16;
  return (unsigned short)u;
}

__device__ __forceinline__ float fdot2f(h2 a, h2 b, float c) {
#if __has_builtin(__builtin_amdgcn_fdot2)
  return __builtin_amdgcn_fdot2(a, b, c, false);
#else
  return fmaf((float)a.x, (float)b.x, fmaf((float)a.y, (float)b.y, c));
#endif
}

// ---------------- f32 -> bf16 convert ----------------
__global__ void convert_bf(const float* __restrict__ src, ushort* __restrict__ dst, int n) {
  int i = blockIdx.x * 256 + threadIdx.x;
  if (i < n) dst[i] = f2bf(src[i]);
}

// ---------------- part encoder ----------------
__global__ void part_encoder(const float* __restrict__ parts, const float* __restrict__ Wpe1,
                             const float* __restrict__ bpe1, const float* __restrict__ Wpe2,
                             const float* __restrict__ bpe2, const float* __restrict__ pos,
                             float* __restrict__ x, ushort* __restrict__ xb) {
  __shared__ float prow[16];
  __shared__ float pe1[128];
  int row = blockIdx.x;
  int s = row & 255;
  int tid = threadIdx.x;  // 128
  if (tid < 16) prow[tid] = parts[row * 16 + tid];
  __syncthreads();
  float a = bpe1[tid];
#pragma unroll
  for (int k = 0; k < 16; ++k) a = fmaf(prow[k], Wpe1[tid * 16 + k], a);
  pe1[tid] = fmaxf(a, 0.0f);
  __syncthreads();
  float a2 = bpe2[tid];
  for (int k = 0; k < 128; ++k) a2 = fmaf(pe1[k], Wpe2[tid * 128 + k], a2);
  x[(size_t)row * 256 + tid] = a2;
  xb[(size_t)row * 256 + tid] = f2bf(a2);
  if (tid < 64) {
    float p = pos[s * 64 + tid];
    x[(size_t)row * 256 + 128 + tid] = p;
    xb[(size_t)row * 256 + 128 + tid] = f2bf(p);
    x[(size_t)row * 256 + 192 + tid] = 0.0f;
    xb[(size_t)row * 256 + 192 + tid] = 0;
  }
}

// ---------------- MFMA bf16 GEMM ----------------
// OUT: 0 = f32 C[m][n]; 1 = bf16 C[m][n]
template <int ACT, int OUT>
__global__ __launch_bounds__(256) void gemm_bf16(
    const ushort* __restrict__ A, const ushort* __restrict__ Wt,
    const float* __restrict__ bias1, const float* __restrict__ bias2,
    void* __restrict__ Cout, int N, int K) {
  int wid = threadIdx.x >> 6;
  int lane = threadIdx.x & 63;
  int m0 = blockIdx.y * 64 + wid * 16;
  int n0 = blockIdx.x * 64;
  int r15 = lane & 15;
  int kg = lane >> 4;
  f32x4 acc0 = {0.f, 0.f, 0.f, 0.f}, acc1 = acc0, acc2 = acc0, acc3 = acc0;
  const ushort* arow = A + (size_t)(m0 + r15) * K + kg * 8;
  const ushort* w0 = Wt + (size_t)(n0 + r15) * K + kg * 8;
  const ushort* w1 = w0 + (size_t)16 * K;
  const ushort* w2 = w0 + (size_t)32 * K;
  const ushort* w3 = w0 + (size_t)48 * K;
  for (int k0 = 0; k0 < K; k0 += 32) {
    bf16x8 af = *(const bf16x8*)(arow + k0);
    bf16x8 b0 = *(const bf16x8*)(w0 + k0);
    bf16x8 b1 = *(const bf16x8*)(w1 + k0);
    bf16x8 b2 = *(const bf16x8*)(w2 + k0);
    bf16x8 b3 = *(const bf16x8*)(w3 + k0);
    acc0 = __builtin_amdgcn_mfma_f32_16x16x32_bf16(af, b0, acc0, 0, 0, 0);
    acc1 = __builtin_amdgcn_mfma_f32_16x16x32_bf16(af, b1, acc1, 0, 0, 0);
    acc2 = __builtin_amdgcn_mfma_f32_16x16x32_bf16(af, b2, acc2, 0, 0, 0);
    acc3 = __builtin_amdgcn_mfma_f32_16x16x32_bf16(af, b3, acc3, 0, 0, 0);
  }
#pragma unroll
  for (int nn = 0; nn < 4; ++nn) {
    f32x4 a = (nn == 0) ? acc0 : (nn == 1) ? acc1 : (nn == 2) ? acc2 : acc3;
    int n = n0 + nn * 16 + r15;
    float bsum = bias1[n] + (bias2 ? bias2[n] : 0.0f);
#pragma unroll
    for (int r = 0; r < 4; ++r) {
      int m = m0 + kg * 4 + r;
      float v = a[r] + bsum;
      if (ACT == 1) v = fmaxf(v, 0.0f);
      if (OUT == 1)
        ((ushort*)Cout)[(size_t)m * N + n] = f2bf(v);
      else
        ((float*)Cout)[(size_t)m * N + n] = v;
    }
  }
}

// ---------------- attention (f32 in, bf16 out) ----------------
__global__ void attn_kernel(const float* __restrict__ qkv, ushort* __restrict__ attout) {
  extern __shared__ float sm[];
  float* kl = sm;
  float* ql = sm + 256 * 33;
  float* sc = sm + 256 * 33 + 32 * 33;
  int qt = blockIdx.x, h = blockIdx.y, b = blockIdx.z;
  int tid = threadIdx.x;  // 256
  {
    int j = tid;
    const float* src = qkv + (size_t)(b * 256 + j) * 768 + 256 + h * 32;
#pragma unroll
    for (int d = 0; d < 32; d += 4) {
      float4 v = *(const float4*)(src + d);
      kl[j * 33 + d] = v.x; kl[j * 33 + d + 1] = v.y; kl[j * 33 + d + 2] = v.z; kl[j * 33 + d + 3] = v.w;
    }
  }
  {
    int i = tid >> 3, d4 = (tid & 7) * 4;
    const float* src = qkv + (size_t)(b * 256 + qt * 32 + i) * 768 + h * 32;
    float4 v = *(const float4*)(src + d4);
    ql[i * 33 + d4] = v.x; ql[i * 33 + d4 + 1] = v.y; ql[i * 33 + d4 + 2] = v.z; ql[i * 33 + d4 + 3] = v.w;
  }
  __syncthreads();
  int i = tid >> 3, c = tid & 7;
  const float scale = 0.17677669529663687f;
  float sv[32];
  float mx = -1e30f;
  for (int jj = 0; jj < 32; ++jj) {
    int j = jj * 8 + c;
    float s = 0.0f;
#pragma unroll
    for (int d = 0; d < 32; ++d) s = fmaf(ql[i * 33 + d], kl[j * 33 + d], s);
    s *= scale;
    sv[jj] = s;
    mx = fmaxf(mx, s);
  }
  mx = fmaxf(mx, __shfl_xor(mx, 1));
  mx = fmaxf(mx, __shfl_xor(mx, 2));
  mx = fmaxf(mx, __shfl_xor(mx, 4));
  float sum = 0.0f;
  for (int jj = 0; jj < 32; ++jj) {
    float p = __expf(sv[jj] - mx);
    sc[i * 257 + jj * 8 + c] = p;
    sum += p;
  }
  sum += __shfl_xor(sum, 1);
  sum += __shfl_xor(sum, 2);
  sum += __shfl_xor(sum, 4);
  float inv = 1.0f / sum;
  __syncthreads();
  float a0 = 0, a1 = 0, a2 = 0, a3 = 0;
  int d0 = c * 4;
  const float* vbase = qkv + 512 + h * 32 + d0;
  for (int j = 0; j < 256; ++j) {
    float p = sc[i * 257 + j];
    float4 v = *(const float4*)(vbase + (size_t)(b * 256 + j) * 768);
    a0 = fmaf(p, v.x, a0); a1 = fmaf(p, v.y, a1); a2 = fmaf(p, v.z, a2); a3 = fmaf(p, v.w, a3);
  }
  int orow = b * 256 + qt * 32 + i;
  ushort4 o4;
  o4.x = f2bf(a0 * inv); o4.y = f2bf(a1 * inv); o4.z = f2bf(a2 * inv); o4.w = f2bf(a3 * inv);
  *(ushort4*)&attout[(size_t)orow * 256 + h * 32 + d0] = o4;
}

// ---------------- LayerNorm(x + o) ----------------
__global__ void ln_residual(float* __restrict__ x, const float* __restrict__ o,
                            const float* __restrict__ g, const float* __restrict__ bt,
                            ushort* __restrict__ xb) {
  int row = blockIdx.x, tid = threadIdx.x;  // 256
  float e = x[(size_t)row * 256 + tid] + o[(size_t)row * 256 + tid];
  float s = e, q = e * e;
#pragma unroll
  for (int off = 32; off >= 1; off >>= 1) {
    s += __shfl_xor(s, off);
    q += __shfl_xor(q, off);
  }
  __shared__ float ps[4], pq[4];
  int wid = tid >> 6, lane = tid & 63;
  if (lane == 0) { ps[wid] = s; pq[wid] = q; }
  __syncthreads();
  float St = ps[0] + ps[1] + ps[2] + ps[3];
  float Qt = pq[0] + pq[1] + pq[2] + pq[3];
  float mean = St * (1.0f / 256.0f);
  float var = Qt * (1.0f / 256.0f) - mean * mean;
  float y = (e - mean) * rsqrtf(var + 1e-5f) * g[tid] + bt[tid];
  x[(size_t)row * 256 + tid] = y;
  xb[(size_t)row * 256 + tid] = f2bf(y);
}

// ---------------- gather dec_in ----------------
__global__ void gather_dec_in(const ushort* __restrict__ encb, const int* __restrict__ ts,
                              ushort* __restrict__ dec_in) {
  int bx = blockIdx.x;
  int t = bx >> 3, b = bx & 7;
  int tid = threadIdx.x;  // 64
  ushort4 v = {0, 0, 0, 0};
  if (t > 0) {
    int sidx = ts[b * 256 + t - 1];
    v = *(const ushort4*)&encb[((size_t)(b * 256 + sidx)) * 256 + tid * 4];
  }
  *(ushort4*)&dec_in[(size_t)bx * 256 + tid * 4] = v;
}

// ---------------- LSTM scan: 2 CUs per batch, zero spill, zero streaming -------
// 16 blocks, bx = s2*8 + b: partner pair (s2=0,1) of batch b lands on the SAME
// XCD (round-robin bx%8). Block owns units [s2*128, s2*128+128), all 4 gates.
// Thread t0: ul=t0>>2, g=t0&3 -> ONE gate-row R = g*256 + s2*128 + ul.
// Weights: cols [0,128) in regs (64 h2; ~95 total regs <= 128 cap -> NO SPILL);
// cols [128,256) in LDS [16][512] uint4 (128 KB, thread-contiguous).
// Quad (4u..4u+3) holds (i,f,g,o); 4 __shfl assemble gates; c,h redundant.
// Exchange (1 partner): ALL-RELAXED atomics; __syncthreads drains vmcnt to
// order data-before-flag; readers relaxed-poll (no acquire -> no buffer_inv).
// 2-deep hg parity race-free: writer can only be 1 step ahead (flag gate).
// Deadlock audit: 16 blocks always co-resident (1/CU); flag induction keeps
// partners within 1 step; flags zeroed per launch inside the graph.
__global__ __attribute__((amdgpu_flat_work_group_size(512, 512), amdgpu_waves_per_eu(2, 2)))
void lstm_scan(const float* __restrict__ Xw, const float* __restrict__ Whh,
               ushort* __restrict__ dec_out, unsigned int* __restrict__ hg,
               unsigned int* __restrict__ flags) {
  extern __shared__ char smem[];
  uint4* wlds = (uint4*)smem;                   // [16][512] uint4 = 128 KB
  _Float16* hbuf = (_Float16*)(smem + 131072);  // [2][256]
  int bx = blockIdx.x;
  int s2 = bx >> 3, b = bx & 7;
  int t0 = threadIdx.x;          // 0..511
  int ul = t0 >> 2, g = t0 & 3;
  int unit = s2 * 128 + ul;      // global unit this quad owns
  int R = g * 256 + unit;        // gate row

  h2 w[64];
  {
    const float4* src = (const float4*)(Whh + (size_t)R * 256);
#pragma unroll
    for (int k = 0; k < 16; ++k) {   // cols 0..127 -> regs
      float4 v = src[2 * k], v2 = src[2 * k + 1];
      w[4 * k + 0] = cvt2(v.x, v.y);  w[4 * k + 1] = cvt2(v.z, v.w);
      w[4 * k + 2] = cvt2(v2.x, v2.y); w[4 * k + 3] = cvt2(v2.z, v2.w);
    }
#pragma unroll
    for (int qc = 0; qc < 16; ++qc) {  // cols 128..255 -> LDS
      float4 v = src[32 + 2 * qc], v2 = src[32 + 2 * qc + 1];
      uint4 u;
      u.x = bcu(cvt2(v.x, v.y));  u.y = bcu(cvt2(v.z, v.w));
      u.z = bcu(cvt2(v2.x, v2.y)); u.w = bcu(cvt2(v2.z, v2.w));
      wlds[qc * 512 + t0] = u;
    }
  }
  if (t0 < 256) { hbuf[t0] = (_Float16)0.0f; hbuf[256 + t0] = (_Float16)0.0f; }
  float c = 0.0f;
  float xnext = Xw[(size_t)b * 1024 + R];
  int qbase = (t0 & 63) & ~3;
  int p_s2 = s2 ^ 1;
  unsigned int* pflag = &flags[p_s2 * 8 + b];
  __syncthreads();

  int cur = 0;
  for (int t = 0; t < 256; ++t) {
    float xcur = xnext;
    if (t < 255) xnext = Xw[(size_t)((t + 1) * 8 + b) * 1024 + R];
    const uint4* hb = (const uint4*)(hbuf + cur * 256);
    float a0 = 0.f, a1 = 0.f, a2 = 0.f, a3 = 0.f;
#pragma unroll
    for (int q = 0; q < 16; ++q) {   // cols 0..127, reg weights
      uint4 hv = hb[q];
      a0 = fdot2f(w[4 * q + 0], bch2(hv.x), a0);
      a1 = fdot2f(w[4 * q + 1], bch2(hv.y), a1);
      a2 = fdot2f(w[4 * q + 2], bch2(hv.z), a2);
      a3 = fdot2f(w[4 * q + 3], bch2(hv.w), a3);
    }
#pragma unroll
    for (int qc = 0; qc < 16; ++qc) {  // cols 128..255, LDS weights
      uint4 hv = hb[16 + qc];
      uint4 wv = wlds[qc * 512 + t0];
      a0 = fdot2f(bch2(wv.x), bch2(hv.x), a0);
      a1 = fdot2f(bch2(wv.y), bch2(hv.y), a1);
      a2 = fdot2f(bch2(wv.z), bch2(hv.z), a2);
      a3 = fdot2f(bch2(wv.w), bch2(hv.w), a3);
    }
    float gsum = (a0 + a1) + (a2 + a3) + xcur;
    float gi = __shfl(gsum, qbase + 0);
    float gf = __shfl(gsum, qbase + 1);
    float gg = __shfl(gsum, qbase + 2);
    float go = __shfl(gsum, qbase + 3);
    c = sigf(gf) * c + sigf(gi) * tanhfast(gg);
    float hv_ = sigf(go) * tanhfast(c);
    _Float16 hf = (_Float16)hv_;
    int nxt = cur ^ 1;
    if (g == 0) hbuf[nxt * 256 + unit] = hf;
    if (g == 1 && t < 255) {
      __hip_atomic_store(&hg[(size_t)((t + 1) & 1) * 2048 + b * 256 + unit],
                         (unsigned int)__builtin_bit_cast(unsigned short, hf),
                         __ATOMIC_RELAXED, __HIP_MEMORY_SCOPE_AGENT);
    }
    if (g == 2) dec_out[((size_t)(b * 256 + t)) * 256 + unit] = f2bf(hv_);
    if (t < 255) {
      __syncthreads();  // drains vmcnt: h data stores globally visible
      if (t0 == 0)
        __hip_atomic_fetch_add(&flags[bx], 1u, __ATOMIC_RELAXED, __HIP_MEMORY_SCOPE_AGENT);
      if (t0 < 128) {   // 2 waves import the partner half (RELAXED poll)
        while (__hip_atomic_load(pflag, __ATOMIC_RELAXED, __HIP_MEMORY_SCOPE_AGENT) <= (unsigned)t)
          __builtin_amdgcn_s_sleep(1);
        unsigned int v = __hip_atomic_load(
            &hg[(size_t)((t + 1) & 1) * 2048 + b * 256 + p_s2 * 128 + t0],
            __ATOMIC_RELAXED, __HIP_MEMORY_SCOPE_AGENT);
        hbuf[nxt * 256 + p_s2 * 128 + t0] = __builtin_bit_cast(_Float16, (unsigned short)v);
      }
      __syncthreads();
    }
    cur ^= 1;
  }
}

// ---------------- pen transpose ----------------
__global__ void transpose_pen(const float* __restrict__ pen, float* __restrict__ penT) {
  int bx = blockIdx.x;
  int b = bx >> 8, h = bx & 255;
  int i = threadIdx.x;  // 256
  penT[(size_t)bx * 256 + i] = pen[((size_t)(b * 256 + i)) * 256 + h];
}

// ---------------- pointer logits ----------------
__global__ void pointer_kernel(const float* __restrict__ pd, const float* __restrict__ penT,
                               const float* __restrict__ vptr, float* __restrict__ out) {
  __shared__ float pdr[256];
  __shared__ float vl[256];
  int bx = blockIdx.x;
  int b = bx >> 8;
  int tid = threadIdx.x;  // 256
  pdr[tid] = pd[(size_t)bx * 256 + tid];
  vl[tid] = vptr[tid];
  __syncthreads();
  const float* pT = penT + (size_t)b * 256 * 256;
  float acc = 0.0f;
  for (int h = 0; h < 256; ++h) {
    acc = fmaf(vl[h], tanhfast(pdr[h] + pT[(size_t)h * 256 + tid]), acc);
  }
  out[(size_t)bx * 256 + tid] = acc;
}

extern "C" void kernel_launch(void* const* d_in, const int* in_sizes, int n_in,
                              void* d_out, int out_size, void* d_ws, size_t ws_size,
                              hipStream_t stream) {
  const float* parts = (const float*)d_in[0];
  const int* ts = (const int*)d_in[1];
  const float* Wpe1 = (const float*)d_in[2];
  const float* bpe1 = (const float*)d_in[3];
  const float* Wpe2 = (const float*)d_in[4];
  const float* bpe2 = (const float*)d_in[5];
  const float* pos = (const float*)d_in[6];
  const float* Wqkv = (const float*)d_in[7];
  const float* bqkv = (const float*)d_in[8];
  const float* Wo = (const float*)d_in[9];
  const float* bo = (const float*)d_in[10];
  const float* ln1g = (const float*)d_in[11];
  const float* ln1b = (const float*)d_in[12];
  const float* W1f = (const float*)d_in[13];
  const float* b1f = (const float*)d_in[14];
  const float* W2f = (const float*)d_in[15];
  const float* b2f = (const float*)d_in[16];
  const float* ln2g = (const float*)d_in[17];
  const float* ln2b = (const float*)d_in[18];
  const float* Wih = (const float*)d_in[19];
  const float* Whh = (const float*)d_in[20];
  const float* bih = (const float*)d_in[21];
  const float* bhh = (const float*)d_in[22];
  const float* Wp = (const float*)d_in[23];
  const float* bp = (const float*)d_in[24];
  const float* vptr = (const float*)d_in[25];
  float* out = (float*)d_out;

  // ---- workspace layout (f32-slot units) ----
  float* W = (float*)d_ws;
  float* xbuf = W;                            // [2048,256] f32, live all
  ushort* xbf = (ushort*)(W + 524288);        // [2048,256] bf16, live all
  float* SCR = W + 786432;                    // 2097152 slots scratch
  float* qkvb = SCR;                          //   encoder: [2048,768] f32
  float* obuf = SCR + 1572864;                //   encoder: [2048,256] f32
  float* Xw = SCR;                            //   decoder: [2048,1024] f32
  float* pdb = SCR;                           //   tail: [2048,256] f32
  float* penb = SCR + 524288;                 //   tail: [2048,256] f32
  float* penTb = SCR + 1048576;               //   tail: [2048,256] f32
  ushort* attbf = (ushort*)(W + 2883584);     // [2048,256] bf16 (encoder)
  ushort* ffbf = (ushort*)(W + 3145728);      // [2048,512] bf16 (encoder)
  ushort* dec_inbf = (ushort*)(W + 3145728);  //   decoder: [2048,256] bf16
  ushort* dec_outbf = (ushort*)(W + 3407872); //   decoder: [2048,256] bf16
  ushort* wqkvbf = (ushort*)(W + 3670016);    // 589824 bf16
  ushort* wobf   = (ushort*)(W + 3964928);    // 196608
  ushort* w1fbf  = (ushort*)(W + 4063232);    // 393216
  ushort* w2fbf  = (ushort*)(W + 4259840);    // 393216
  ushort* wihbf  = (ushort*)(W + 4456448);    // 262144
  ushort* wpbf   = (ushort*)(W + 4587520);    // 65536
  unsigned int* hg = (unsigned int*)(W + 4620288);     // [2][8][256] u32 (16 KB)
  unsigned int* flags = (unsigned int*)(W + 4624384);  // [16] u32

  const int attnLDS = (256 * 33 + 32 * 33 + 32 * 257) * 4;  // 70912 B
  const int scanLDS = 131072 + 1024;                        // 132096 B
  hipFuncSetAttribute((const void*)attn_kernel, hipFuncAttributeMaxDynamicSharedMemorySize, attnLDS);
  hipFuncSetAttribute((const void*)lstm_scan, hipFuncAttributeMaxDynamicSharedMemorySize, scanLDS);

  // weight conversions
  convert_bf<<<(589824 + 255) / 256, 256, 0, stream>>>(Wqkv, wqkvbf, 589824);
  convert_bf<<<(196608 + 255) / 256, 256, 0, stream>>>(Wo, wobf, 196608);
  convert_bf<<<(393216 + 255) / 256, 256, 0, stream>>>(W1f, w1fbf, 393216);
  convert_bf<<<(393216 + 255) / 256, 256, 0, stream>>>(W2f, w2fbf, 393216);
  convert_bf<<<(262144 + 255) / 256, 256, 0, stream>>>(Wih, wihbf, 262144);
  convert_bf<<<(65536 + 255) / 256, 256, 0, stream>>>(Wp, wpbf, 65536);

  part_encoder<<<2048, 128, 0, stream>>>(parts, Wpe1, bpe1, Wpe2, bpe2, pos, xbuf, xbf);
  for (int l = 0; l < 3; ++l) {
    gemm_bf16<0, 0><<<dim3(12, 32), 256, 0, stream>>>(xbf, wqkvbf + (size_t)l * 196608,
                                                      bqkv + l * 768, nullptr, qkvb, 768, 256);
    attn_kernel<<<dim3(8, 8, 8), 256, attnLDS, stream>>>(qkvb, attbf);
    gemm_bf16<0, 0><<<dim3(4, 32), 256, 0, stream>>>(attbf, wobf + (size_t)l * 65536,
                                                     bo + l * 256, nullptr, obuf, 256, 256);
    ln_residual<<<2048, 256, 0, stream>>>(xbuf, obuf, ln1g + l * 256, ln1b + l * 256, xbf);
    gemm_bf16<1, 1><<<dim3(8, 32), 256, 0, stream>>>(xbf, w1fbf + (size_t)l * 131072,
                                                     b1f + l * 512, nullptr, ffbf, 512, 256);
    gemm_bf16<0, 0><<<dim3(4, 32), 256, 0, stream>>>(ffbf, w2fbf + (size_t)l * 131072,
                                                     b2f + l * 256, nullptr, obuf, 256, 512);
    ln_residual<<<2048, 256, 0, stream>>>(xbuf, obuf, ln2g + l * 256, ln2b + l * 256, xbf);
  }
  gather_dec_in<<<2048, 64, 0, stream>>>(xbf, ts, dec_inbf);
  gemm_bf16<0, 0><<<dim3(16, 32), 256, 0, stream>>>(dec_inbf, wihbf, bih, bhh, Xw, 1024, 256);
  hipMemsetAsync(flags, 0, 16 * sizeof(unsigned int), stream);
  lstm_scan<<<16, 512, scanLDS, stream>>>(Xw, Whh, dec_outbf, hg, flags);
  gemm_bf16<0, 0><<<dim3(4, 32), 256, 0, stream>>>(dec_outbf, wpbf, bp, nullptr, pdb, 256, 256);
  gemm_bf16<0, 0><<<dim3(4, 32), 256, 0, stream>>>(xbf, wpbf, bp, nullptr, penb, 256, 256);
  transpose_pen<<<2048, 256, 0, stream>>>(penb, penTb);
  pointer_kernel<<<2048, 256, 0, stream>>>(pdb, penTb, vptr, out);
}

// Round 11
// 859.058 us; speedup vs baseline: 1.7505x; 1.2020x over previous
//
#include <hip/hip_runtime.h>
#include <cstdint>
#include <cstddef>

typedef _Float16 h2 __attribute__((ext_vector_type(2)));
typedef short bf16x8 __attribute__((ext_vector_type(8)));
typedef float f32x4 __attribute__((ext_vector_type(4)));

__device__ __forceinline__ float sigf(float x) { return 1.0f / (1.0f + __expf(-x)); }
__device__ __forceinline__ float tanhfast(float x) {
  float e = __expf(-2.0f * fabsf(x));
  float t = (1.0f - e) / (1.0f + e);
  return copysignf(t, x);
}
__device__ __forceinline__ h2 cvt2(float a, float b) {
  h2 r; r.x = (_Float16)a; r.y = (_Float16)b; return r;
}
__device__ __forceinline__ h2 bch2(unsigned int u) { return __builtin_bit_cast(h2, u); }
__device__ __forceinline__ unsigned int bcu(h2 v) { return __builtin_bit_cast(unsigned int, v); }
__device__ __forceinline__ unsigned short f2bf(float f) {
  unsigned int u = __float_as_uint(f);
  u = (u + 0x7fffu + ((u >> 16) & 1u)) >> 16;
  return (unsigned short)u;
}

__device__ __forceinline__ float fdot2f(h2 a, h2 b, float c) {
#if __has_builtin(__builtin_amdgcn_fdot2)
  return __builtin_amdgcn_fdot2(a, b, c, false);
#else
  return fmaf((float)a.x, (float)b.x, fmaf((float)a.y, (float)b.y, c));
#endif
}

// ---------------- f32 -> bf16 convert ----------------
__global__ void convert_bf(const float* __restrict__ src, ushort* __restrict__ dst, int n) {
  int i = blockIdx.x * 256 + threadIdx.x;
  if (i < n) dst[i] = f2bf(src[i]);
}

// ---------------- part encoder ----------------
__global__ void part_encoder(const float* __restrict__ parts, const float* __restrict__ Wpe1,
                             const float* __restrict__ bpe1, const float* __restrict__ Wpe2,
                             const float* __restrict__ bpe2, const float* __restrict__ pos,
                             float* __restrict__ x, ushort* __restrict__ xb) {
  __shared__ float prow[16];
  __shared__ float pe1[128];
  int row = blockIdx.x;
  int s = row & 255;
  int tid = threadIdx.x;  // 128
  if (tid < 16) prow[tid] = parts[row * 16 + tid];
  __syncthreads();
  float a = bpe1[tid];
#pragma unroll
  for (int k = 0; k < 16; ++k) a = fmaf(prow[k], Wpe1[tid * 16 + k], a);
  pe1[tid] = fmaxf(a, 0.0f);
  __syncthreads();
  float a2 = bpe2[tid];
  for (int k = 0; k < 128; ++k) a2 = fmaf(pe1[k], Wpe2[tid * 128 + k], a2);
  x[(size_t)row * 256 + tid] = a2;
  xb[(size_t)row * 256 + tid] = f2bf(a2);
  if (tid < 64) {
    float p = pos[s * 64 + tid];
    x[(size_t)row * 256 + 128 + tid] = p;
    xb[(size_t)row * 256 + 128 + tid] = f2bf(p);
    x[(size_t)row * 256 + 192 + tid] = 0.0f;
    xb[(size_t)row * 256 + 192 + tid] = 0;
  }
}

// ---------------- MFMA bf16 GEMM ----------------
// OUT: 0 = f32 C[m][n]; 1 = bf16 C[m][n]; 3 = f32 TRANSPOSED penT[(b*256+n)*256 + m%256]
template <int ACT, int OUT>
__global__ __launch_bounds__(256) void gemm_bf16(
    const ushort* __restrict__ A, const ushort* __restrict__ Wt,
    const float* __restrict__ bias1, const float* __restrict__ bias2,
    void* __restrict__ Cout, int N, int K) {
  int wid = threadIdx.x >> 6;
  int lane = threadIdx.x & 63;
  int m0 = blockIdx.y * 64 + wid * 16;
  int n0 = blockIdx.x * 64;
  int r15 = lane & 15;
  int kg = lane >> 4;
  f32x4 acc0 = {0.f, 0.f, 0.f, 0.f}, acc1 = acc0, acc2 = acc0, acc3 = acc0;
  const ushort* arow = A + (size_t)(m0 + r15) * K + kg * 8;
  const ushort* w0 = Wt + (size_t)(n0 + r15) * K + kg * 8;
  const ushort* w1 = w0 + (size_t)16 * K;
  const ushort* w2 = w0 + (size_t)32 * K;
  const ushort* w3 = w0 + (size_t)48 * K;
  for (int k0 = 0; k0 < K; k0 += 32) {
    bf16x8 af = *(const bf16x8*)(arow + k0);
    bf16x8 b0 = *(const bf16x8*)(w0 + k0);
    bf16x8 b1 = *(const bf16x8*)(w1 + k0);
    bf16x8 b2 = *(const bf16x8*)(w2 + k0);
    bf16x8 b3 = *(const bf16x8*)(w3 + k0);
    acc0 = __builtin_amdgcn_mfma_f32_16x16x32_bf16(af, b0, acc0, 0, 0, 0);
    acc1 = __builtin_amdgcn_mfma_f32_16x16x32_bf16(af, b1, acc1, 0, 0, 0);
    acc2 = __builtin_amdgcn_mfma_f32_16x16x32_bf16(af, b2, acc2, 0, 0, 0);
    acc3 = __builtin_amdgcn_mfma_f32_16x16x32_bf16(af, b3, acc3, 0, 0, 0);
  }
#pragma unroll
  for (int nn = 0; nn < 4; ++nn) {
    f32x4 a = (nn == 0) ? acc0 : (nn == 1) ? acc1 : (nn == 2) ? acc2 : acc3;
    int n = n0 + nn * 16 + r15;
    float bsum = bias1[n] + (bias2 ? bias2[n] : 0.0f);
    if (OUT == 3) {
      int b = m0 >> 8;
      int mloc = (m0 & 255) + kg * 4;
      float4 o4 = {a[0] + bsum, a[1] + bsum, a[2] + bsum, a[3] + bsum};
      *(float4*)&((float*)Cout)[((size_t)(b * 256 + n)) * 256 + mloc] = o4;
    } else {
#pragma unroll
      for (int r = 0; r < 4; ++r) {
        int m = m0 + kg * 4 + r;
        float v = a[r] + bsum;
        if (ACT == 1) v = fmaxf(v, 0.0f);
        if (OUT == 1)
          ((ushort*)Cout)[(size_t)m * N + n] = f2bf(v);
        else
          ((float*)Cout)[(size_t)m * N + n] = v;
      }
    }
  }
}

// ---------------- attention (f32 in, bf16 out) ----------------
__global__ void attn_kernel(const float* __restrict__ qkv, ushort* __restrict__ attout) {
  extern __shared__ float sm[];
  float* kl = sm;
  float* ql = sm + 256 * 33;
  float* sc = sm + 256 * 33 + 32 * 33;
  int qt = blockIdx.x, h = blockIdx.y, b = blockIdx.z;
  int tid = threadIdx.x;  // 256
  {
    int j = tid;
    const float* src = qkv + (size_t)(b * 256 + j) * 768 + 256 + h * 32;
#pragma unroll
    for (int d = 0; d < 32; d += 4) {
      float4 v = *(const float4*)(src + d);
      kl[j * 33 + d] = v.x; kl[j * 33 + d + 1] = v.y; kl[j * 33 + d + 2] = v.z; kl[j * 33 + d + 3] = v.w;
    }
  }
  {
    int i = tid >> 3, d4 = (tid & 7) * 4;
    const float* src = qkv + (size_t)(b * 256 + qt * 32 + i) * 768 + h * 32;
    float4 v = *(const float4*)(src + d4);
    ql[i * 33 + d4] = v.x; ql[i * 33 + d4 + 1] = v.y; ql[i * 33 + d4 + 2] = v.z; ql[i * 33 + d4 + 3] = v.w;
  }
  __syncthreads();
  int i = tid >> 3, c = tid & 7;
  const float scale = 0.17677669529663687f;
  float sv[32];
  float mx = -1e30f;
  for (int jj = 0; jj < 32; ++jj) {
    int j = jj * 8 + c;
    float s = 0.0f;
#pragma unroll
    for (int d = 0; d < 32; ++d) s = fmaf(ql[i * 33 + d], kl[j * 33 + d], s);
    s *= scale;
    sv[jj] = s;
    mx = fmaxf(mx, s);
  }
  mx = fmaxf(mx, __shfl_xor(mx, 1));
  mx = fmaxf(mx, __shfl_xor(mx, 2));
  mx = fmaxf(mx, __shfl_xor(mx, 4));
  float sum = 0.0f;
  for (int jj = 0; jj < 32; ++jj) {
    float p = __expf(sv[jj] - mx);
    sc[i * 257 + jj * 8 + c] = p;
    sum += p;
  }
  sum += __shfl_xor(sum, 1);
  sum += __shfl_xor(sum, 2);
  sum += __shfl_xor(sum, 4);
  float inv = 1.0f / sum;
  __syncthreads();
  float a0 = 0, a1 = 0, a2 = 0, a3 = 0;
  int d0 = c * 4;
  const float* vbase = qkv + 512 + h * 32 + d0;
  for (int j = 0; j < 256; ++j) {
    float p = sc[i * 257 + j];
    float4 v = *(const float4*)(vbase + (size_t)(b * 256 + j) * 768);
    a0 = fmaf(p, v.x, a0); a1 = fmaf(p, v.y, a1); a2 = fmaf(p, v.z, a2); a3 = fmaf(p, v.w, a3);
  }
  int orow = b * 256 + qt * 32 + i;
  ushort4 o4;
  o4.x = f2bf(a0 * inv); o4.y = f2bf(a1 * inv); o4.z = f2bf(a2 * inv); o4.w = f2bf(a3 * inv);
  *(ushort4*)&attout[(size_t)orow * 256 + h * 32 + d0] = o4;
}

// ---------------- LayerNorm(x + o) ----------------
__global__ void ln_residual(float* __restrict__ x, const float* __restrict__ o,
                            const float* __restrict__ g, const float* __restrict__ bt,
                            ushort* __restrict__ xb) {
  int row = blockIdx.x, tid = threadIdx.x;  // 256
  float e = x[(size_t)row * 256 + tid] + o[(size_t)row * 256 + tid];
  float s = e, q = e * e;
#pragma unroll
  for (int off = 32; off >= 1; off >>= 1) {
    s += __shfl_xor(s, off);
    q += __shfl_xor(q, off);
  }
  __shared__ float ps[4], pq[4];
  int wid = tid >> 6, lane = tid & 63;
  if (lane == 0) { ps[wid] = s; pq[wid] = q; }
  __syncthreads();
  float St = ps[0] + ps[1] + ps[2] + ps[3];
  float Qt = pq[0] + pq[1] + pq[2] + pq[3];
  float mean = St * (1.0f / 256.0f);
  float var = Qt * (1.0f / 256.0f) - mean * mean;
  float y = (e - mean) * rsqrtf(var + 1e-5f) * g[tid] + bt[tid];
  x[(size_t)row * 256 + tid] = y;
  xb[(size_t)row * 256 + tid] = f2bf(y);
}

// ---------------- gather dec_in ----------------
__global__ void gather_dec_in(const ushort* __restrict__ encb, const int* __restrict__ ts,
                              ushort* __restrict__ dec_in) {
  int bx = blockIdx.x;
  int t = bx >> 3, b = bx & 7;
  int tid = threadIdx.x;  // 64
  ushort4 v = {0, 0, 0, 0};
  if (t > 0) {
    int sidx = ts[b * 256 + t - 1];
    v = *(const ushort4*)&encb[((size_t)(b * 256 + sidx)) * 256 + tid * 4];
  }
  *(ushort4*)&dec_in[(size_t)bx * 256 + tid * 4] = v;
}

// ---------------- LSTM scan v1024: FULL Whh residency, 1 block/batch ----------
// 1024 threads; thread R owns gate-row R (all 1024 rows covered). Weights:
// cols 0..191 in VGPRs (96 h2 = 96 regs -> needs the 128-reg grant), cols
// 192..255 in LDS [8][1024] uint4 (128 KB). Total on-CU = 393 KB regs +
// 128 KB LDS >= 512 KB Whh: ZERO streaming, ZERO spill (if granted).
// waves_per_eu(2) is MIN-ONLY: budget 256/2 = 128 regs without forbidding the
// 4-waves/EU residency a 1024-thread block needs. If the compiler clamps to 64
// it MUST spill the 96 weight regs -> localSizeBytes > 0 -> host falls back.
// Gate exchange via gp[1024] f32 in LDS; c,h update on threads R<256.
__global__ __attribute__((amdgpu_flat_work_group_size(1024, 1024), amdgpu_waves_per_eu(2)))
void lstm_scan1024(const float* __restrict__ Xw, const float* __restrict__ Whh,
                   ushort* __restrict__ dec_out) {
  extern __shared__ char smem[];
  uint4* wlds = (uint4*)smem;                     // [8][1024] uint4 = 128 KB
  _Float16* hbuf = (_Float16*)(smem + 131072);    // [2][256] = 1 KB
  float* gp = (float*)(smem + 131072 + 1024);     // [1024] = 4 KB
  int b = blockIdx.x;
  int R = threadIdx.x;  // 0..1023 = gate row

  h2 w[96];
  {
    const float4* src = (const float4*)(Whh + (size_t)R * 256);
#pragma unroll
    for (int k = 0; k < 48; ++k) {   // cols 0..191 -> regs
      float4 v = src[k];
      w[2 * k] = cvt2(v.x, v.y);
      w[2 * k + 1] = cvt2(v.z, v.w);
    }
#pragma unroll
    for (int qc = 0; qc < 8; ++qc) { // cols 192..255 -> LDS
      float4 v = src[48 + 2 * qc], v2 = src[48 + 2 * qc + 1];
      uint4 u;
      u.x = bcu(cvt2(v.x, v.y));  u.y = bcu(cvt2(v.z, v.w));
      u.z = bcu(cvt2(v2.x, v2.y)); u.w = bcu(cvt2(v2.z, v2.w));
      wlds[qc * 1024 + R] = u;
    }
  }
  if (R < 256) { hbuf[R] = (_Float16)0.0f; hbuf[256 + R] = (_Float16)0.0f; }
  float c = 0.0f;
  float xnext = Xw[(size_t)b * 1024 + R];
  __syncthreads();

  int cur = 0;
  for (int t = 0; t < 256; ++t) {
    float xcur = xnext;
    if (t < 255) xnext = Xw[(size_t)((t + 1) * 8 + b) * 1024 + R];
    const uint4* hb = (const uint4*)(hbuf + cur * 256);
    float a0 = 0.f, a1 = 0.f, a2 = 0.f, a3 = 0.f;
#pragma unroll
    for (int q = 0; q < 24; ++q) {   // cols 0..191 (reg weights; h broadcast)
      uint4 hv = hb[q];
      a0 = fdot2f(w[4 * q + 0], bch2(hv.x), a0);
      a1 = fdot2f(w[4 * q + 1], bch2(hv.y), a1);
      a2 = fdot2f(w[4 * q + 2], bch2(hv.z), a2);
      a3 = fdot2f(w[4 * q + 3], bch2(hv.w), a3);
    }
#pragma unroll
    for (int qc = 0; qc < 8; ++qc) { // cols 192..255 (LDS weights)
      uint4 hv = hb[24 + qc];
      uint4 wv = wlds[qc * 1024 + R];
      a0 = fdot2f(bch2(wv.x), bch2(hv.x), a0);
      a1 = fdot2f(bch2(wv.y), bch2(hv.y), a1);
      a2 = fdot2f(bch2(wv.z), bch2(hv.z), a2);
      a3 = fdot2f(bch2(wv.w), bch2(hv.w), a3);
    }
    gp[R] = (a0 + a1) + (a2 + a3) + xcur;
    __syncthreads();
    int nxt = cur ^ 1;
    if (R < 256) {
      float gi = gp[R], gf = gp[256 + R], gg = gp[512 + R], go = gp[768 + R];
      c = sigf(gf) * c + sigf(gi) * tanhfast(gg);
      float hv_ = sigf(go) * tanhfast(c);
      hbuf[nxt * 256 + R] = (_Float16)hv_;
      dec_out[((size_t)(b * 256 + t)) * 256 + R] = f2bf(hv_);
    }
    __syncthreads();
    cur = nxt;
  }
}

// ---------------- LSTM scan v512: PROVEN fallback (R6: 479 us) ----------------
__global__ __attribute__((amdgpu_flat_work_group_size(512, 512), amdgpu_waves_per_eu(1, 1)))
void lstm_scan512(const float* __restrict__ Xw, const float* __restrict__ Whh,
                  ushort* __restrict__ dec_out) {
  extern __shared__ char smem[];
  uint4* wlds = (uint4*)smem;                 // [8][1024] uint4 = 128 KB
  h2* hbuf = (h2*)(smem + 131072);            // [2][128] h2
  int b = blockIdx.x;
  int t0 = threadIdx.x;        // 0..511
  int u = t0 >> 1, p = t0 & 1;
  int rA = u + 256 * p;        // i (p0) / f (p1)
  int rB = u + 512 + 256 * p;  // g (p0) / o (p1)

  h2 w0[96], w1[96];
  {
    const float4* sA = (const float4*)(Whh + (size_t)rA * 256);
    const float4* sB = (const float4*)(Whh + (size_t)rB * 256);
#pragma unroll
    for (int k = 0; k < 48; ++k) {
      float4 v = sA[k];
      w0[2 * k] = cvt2(v.x, v.y);
      w0[2 * k + 1] = cvt2(v.z, v.w);
    }
#pragma unroll
    for (int k = 0; k < 48; ++k) {
      float4 v = sB[k];
      w1[2 * k] = cvt2(v.x, v.y);
      w1[2 * k + 1] = cvt2(v.z, v.w);
    }
#pragma unroll
    for (int qc = 0; qc < 8; ++qc) {
      float4 vA0 = sA[48 + 2 * qc], vA1 = sA[48 + 2 * qc + 1];
      float4 vB0 = sB[48 + 2 * qc], vB1 = sB[48 + 2 * qc + 1];
      uint4 uA, uB;
      uA.x = bcu(cvt2(vA0.x, vA0.y)); uA.y = bcu(cvt2(vA0.z, vA0.w));
      uA.z = bcu(cvt2(vA1.x, vA1.y)); uA.w = bcu(cvt2(vA1.z, vA1.w));
      uB.x = bcu(cvt2(vB0.x, vB0.y)); uB.y = bcu(cvt2(vB0.z, vB0.w));
      uB.z = bcu(cvt2(vB1.x, vB1.y)); uB.w = bcu(cvt2(vB1.z, vB1.w));
      wlds[qc * 1024 + rA] = uA;
      wlds[qc * 1024 + rB] = uB;
    }
  }
  if (t0 < 128) ((uint4*)hbuf)[t0 & 63] = make_uint4(0, 0, 0, 0);
  float c = 0.0f;
  float xnA = Xw[(size_t)b * 1024 + rA];
  float xnB = Xw[(size_t)b * 1024 + rB];
  __syncthreads();

  for (int t = 0; t < 256; ++t) {
    float xwA = xnA, xwB = xnB;
    if (t < 255) {
      const float* xp = Xw + (size_t)((t + 1) * 8 + b) * 1024;
      xnA = xp[rA]; xnB = xp[rB];
    }
    const uint4* hb = (const uint4*)(hbuf + (size_t)(t & 1) * 128);
    float a0 = 0.0f, a1 = 0.0f;
#pragma unroll
    for (int q = 0; q < 24; ++q) {
      uint4 hv = hb[q];
      h2 hx = bch2(hv.x), hy = bch2(hv.y), hz = bch2(hv.z), hw = bch2(hv.w);
      a0 = fdot2f(w0[4 * q], hx, a0); a0 = fdot2f(w0[4 * q + 1], hy, a0);
      a0 = fdot2f(w0[4 * q + 2], hz, a0); a0 = fdot2f(w0[4 * q + 3], hw, a0);
      a1 = fdot2f(w1[4 * q], hx, a1); a1 = fdot2f(w1[4 * q + 1], hy, a1);
      a1 = fdot2f(w1[4 * q + 2], hz, a1); a1 = fdot2f(w1[4 * q + 3], hw, a1);
    }
#pragma unroll
    for (int qc = 0; qc < 8; ++qc) {
      uint4 hv = hb[24 + qc];
      h2 hx = bch2(hv.x), hy = bch2(hv.y), hz = bch2(hv.z), hw = bch2(hv.w);
      uint4 uA = wlds[qc * 1024 + rA];
      uint4 uB = wlds[qc * 1024 + rB];
      a0 = fdot2f(bch2(uA.x), hx, a0); a0 = fdot2f(bch2(uA.y), hy, a0);
      a0 = fdot2f(bch2(uA.z), hz, a0); a0 = fdot2f(bch2(uA.w), hw, a0);
      a1 = fdot2f(bch2(uB.x), hx, a1); a1 = fdot2f(bch2(uB.y), hy, a1);
      a1 = fdot2f(bch2(uB.z), hz, a1); a1 = fdot2f(bch2(uB.w), hw, a1);
    }
    a0 += xwA;
    a1 += xwB;
    float ev = sigf(a0) * tanhfast(a1);
    float ep = __shfl_xor(ev, 1);
    if (p == 1) {
      c = sigf(a0) * c + ep;
      float hv_ = sigf(a1) * tanhfast(c);
      ((_Float16*)(hbuf + (size_t)((t + 1) & 1) * 128))[u] = (_Float16)hv_;
      dec_out[((size_t)(b * 256 + t)) * 256 + u] = f2bf(hv_);
    }
    __syncthreads();
  }
}

// ---------------- pointer logits ----------------
__global__ void pointer_kernel(const float* __restrict__ pd, const float* __restrict__ penT,
                               const float* __restrict__ vptr, float* __restrict__ out) {
  __shared__ float pdr[256];
  __shared__ float vl[256];
  int bx = blockIdx.x;
  int b = bx >> 8;
  int tid = threadIdx.x;  // 256
  pdr[tid] = pd[(size_t)bx * 256 + tid];
  vl[tid] = vptr[tid];
  __syncthreads();
  const float* pT = penT + (size_t)b * 256 * 256;
  float acc = 0.0f;
  for (int h = 0; h < 256; ++h) {
    acc = fmaf(vl[h], tanhfast(pdr[h] + pT[(size_t)h * 256 + tid]), acc);
  }
  out[(size_t)bx * 256 + tid] = acc;
}

extern "C" void kernel_launch(void* const* d_in, const int* in_sizes, int n_in,
                              void* d_out, int out_size, void* d_ws, size_t ws_size,
                              hipStream_t stream) {
  const float* parts = (const float*)d_in[0];
  const int* ts = (const int*)d_in[1];
  const float* Wpe1 = (const float*)d_in[2];
  const float* bpe1 = (const float*)d_in[3];
  const float* Wpe2 = (const float*)d_in[4];
  const float* bpe2 = (const float*)d_in[5];
  const float* pos = (const float*)d_in[6];
  const float* Wqkv = (const float*)d_in[7];
  const float* bqkv = (const float*)d_in[8];
  const float* Wo = (const float*)d_in[9];
  const float* bo = (const float*)d_in[10];
  const float* ln1g = (const float*)d_in[11];
  const float* ln1b = (const float*)d_in[12];
  const float* W1f = (const float*)d_in[13];
  const float* b1f = (const float*)d_in[14];
  const float* W2f = (const float*)d_in[15];
  const float* b2f = (const float*)d_in[16];
  const float* ln2g = (const float*)d_in[17];
  const float* ln2b = (const float*)d_in[18];
  const float* Wih = (const float*)d_in[19];
  const float* Whh = (const float*)d_in[20];
  const float* bih = (const float*)d_in[21];
  const float* bhh = (const float*)d_in[22];
  const float* Wp = (const float*)d_in[23];
  const float* bp = (const float*)d_in[24];
  const float* vptr = (const float*)d_in[25];
  float* out = (float*)d_out;

  // ---- workspace layout (f32-slot units) ----
  float* W = (float*)d_ws;
  float* xbuf = W;                            // [2048,256] f32, live all
  ushort* xbf = (ushort*)(W + 524288);        // [2048,256] bf16, live all
  float* SCR = W + 786432;                    // 2097152 slots scratch
  float* qkvb = SCR;                          //   encoder: [2048,768] f32
  float* obuf = SCR + 1572864;                //   encoder: [2048,256] f32
  float* Xw = SCR;                            //   decoder: [2048,1024] f32
  float* pdb = SCR;                           //   tail: [2048,256] f32
  float* penTb = SCR + 1048576;               //   tail: [8,256,256] f32 transposed
  ushort* attbf = (ushort*)(W + 2883584);     // [2048,256] bf16 (encoder)
  ushort* ffbf = (ushort*)(W + 3145728);      // [2048,512] bf16 (encoder)
  ushort* dec_inbf = (ushort*)(W + 3145728);  //   decoder: [2048,256] bf16
  ushort* dec_outbf = (ushort*)(W + 3407872); //   decoder: [2048,256] bf16
  ushort* wqkvbf = (ushort*)(W + 3670016);    // 589824 bf16
  ushort* wobf   = (ushort*)(W + 3964928);    // 196608
  ushort* w1fbf  = (ushort*)(W + 4063232);    // 393216
  ushort* w2fbf  = (ushort*)(W + 4259840);    // 393216
  ushort* wihbf  = (ushort*)(W + 4456448);    // 262144
  ushort* wpbf   = (ushort*)(W + 4587520);    // 65536

  const int attnLDS = (256 * 33 + 32 * 33 + 32 * 257) * 4;  // 70912 B
  const int scan512LDS = 131072 + 1024;                     // 132096 B
  const int scan1024LDS = 131072 + 1024 + 4096;             // 136192 B
  hipFuncSetAttribute((const void*)attn_kernel, hipFuncAttributeMaxDynamicSharedMemorySize, attnLDS);
  hipFuncSetAttribute((const void*)lstm_scan512, hipFuncAttributeMaxDynamicSharedMemorySize, scan512LDS);
  hipFuncSetAttribute((const void*)lstm_scan1024, hipFuncAttributeMaxDynamicSharedMemorySize, scan1024LDS);

  // Spill-guard: use the full-residency 1024-thread scan only if it compiled
  // with zero scratch (localSizeBytes==0 => the 128-reg grant landed, no spill).
  // Deterministic across calls (pure host query of compiled-binary attributes).
  hipFuncAttributes fa1024{};
  bool use1024 = false;
  if (hipFuncGetAttributes(&fa1024, (const void*)lstm_scan1024) == hipSuccess)
    use1024 = (fa1024.localSizeBytes == 0 && fa1024.numRegs >= 100);

  // weight conversions
  convert_bf<<<(589824 + 255) / 256, 256, 0, stream>>>(Wqkv, wqkvbf, 589824);
  convert_bf<<<(196608 + 255) / 256, 256, 0, stream>>>(Wo, wobf, 196608);
  convert_bf<<<(393216 + 255) / 256, 256, 0, stream>>>(W1f, w1fbf, 393216);
  convert_bf<<<(393216 + 255) / 256, 256, 0, stream>>>(W2f, w2fbf, 393216);
  convert_bf<<<(262144 + 255) / 256, 256, 0, stream>>>(Wih, wihbf, 262144);
  convert_bf<<<(65536 + 255) / 256, 256, 0, stream>>>(Wp, wpbf, 65536);

  part_encoder<<<2048, 128, 0, stream>>>(parts, Wpe1, bpe1, Wpe2, bpe2, pos, xbuf, xbf);
  for (int l = 0; l < 3; ++l) {
    gemm_bf16<0, 0><<<dim3(12, 32), 256, 0, stream>>>(xbf, wqkvbf + (size_t)l * 196608,
                                                      bqkv + l * 768, nullptr, qkvb, 768, 256);
    attn_kernel<<<dim3(8, 8, 8), 256, attnLDS, stream>>>(qkvb, attbf);
    gemm_bf16<0, 0><<<dim3(4, 32), 256, 0, stream>>>(attbf, wobf + (size_t)l * 65536,
                                                     bo + l * 256, nullptr, obuf, 256, 256);
    ln_residual<<<2048, 256, 0, stream>>>(xbuf, obuf, ln1g + l * 256, ln1b + l * 256, xbf);
    gemm_bf16<1, 1><<<dim3(8, 32), 256, 0, stream>>>(xbf, w1fbf + (size_t)l * 131072,
                                                     b1f + l * 512, nullptr, ffbf, 512, 256);
    gemm_bf16<0, 0><<<dim3(4, 32), 256, 0, stream>>>(ffbf, w2fbf + (size_t)l * 131072,
                                                     b2f + l * 256, nullptr, obuf, 256, 512);
    ln_residual<<<2048, 256, 0, stream>>>(xbuf, obuf, ln2g + l * 256, ln2b + l * 256, xbf);
  }
  gather_dec_in<<<2048, 64, 0, stream>>>(xbf, ts, dec_inbf);
  gemm_bf16<0, 0><<<dim3(16, 32), 256, 0, stream>>>(dec_inbf, wihbf, bih, bhh, Xw, 1024, 256);
  if (use1024)
    lstm_scan1024<<<8, 1024, scan1024LDS, stream>>>(Xw, Whh, dec_outbf);
  else
    lstm_scan512<<<8, 512, scan512LDS, stream>>>(Xw, Whh, dec_outbf);
  gemm_bf16<0, 0><<<dim3(4, 32), 256, 0, stream>>>(dec_outbf, wpbf, bp, nullptr, pdb, 256, 256);
  // pen GEMM writes penT DIRECTLY (transposed f32) -> transpose_pen eliminated
  gemm_bf16<0, 3><<<dim3(4, 32), 256, 0, stream>>>(xbf, wpbf, bp, nullptr, penTb, 256, 256);
  pointer_kernel<<<2048, 256, 0, stream>>>(pdb, penTb, vptr, out);
}

// Round 13
// 849.107 us; speedup vs baseline: 1.7710x; 1.0117x over previous
//
#include <hip/hip_runtime.h>
#include <cstdint>
#include <cstddef>

typedef _Float16 h2 __attribute__((ext_vector_type(2)));
typedef short bf16x8 __attribute__((ext_vector_type(8)));
typedef float f32x4 __attribute__((ext_vector_type(4)));

#if __has_builtin(__builtin_amdgcn_sdot4)
#define HAVE_SDOT4 1
#else
#define HAVE_SDOT4 0
#endif

__device__ __forceinline__ float sigf(float x) { return 1.0f / (1.0f + __expf(-x)); }
__device__ __forceinline__ float tanhfast(float x) {
  float e = __expf(-2.0f * fabsf(x));
  float t = (1.0f - e) / (1.0f + e);
  return copysignf(t, x);
}
__device__ __forceinline__ h2 cvt2(float a, float b) {
  h2 r; r.x = (_Float16)a; r.y = (_Float16)b; return r;
}
__device__ __forceinline__ h2 bch2(unsigned int u) { return __builtin_bit_cast(h2, u); }
__device__ __forceinline__ unsigned int bcu(h2 v) { return __builtin_bit_cast(unsigned int, v); }
__device__ __forceinline__ unsigned short f2bf(float f) {
  unsigned int u = __float_as_uint(f);
  u = (u + 0x7fffu + ((u >> 16) & 1u)) >> 16;
  return (unsigned short)u;
}

__device__ __forceinline__ float fdot2f(h2 a, h2 b, float c) {
#if __has_builtin(__builtin_amdgcn_fdot2)
  return __builtin_amdgcn_fdot2(a, b, c, false);
#else
  return fmaf((float)a.x, (float)b.x, fmaf((float)a.y, (float)b.y, c));
#endif
}

// ---------------- fused f32 -> bf16 convert for ALL weights (1 launch) ---------
__global__ void convert_all(const float* __restrict__ s0, ushort* __restrict__ d0,
                            const float* __restrict__ s1, ushort* __restrict__ d1,
                            const float* __restrict__ s2, ushort* __restrict__ d2,
                            const float* __restrict__ s3, ushort* __restrict__ d3,
                            const float* __restrict__ s4, ushort* __restrict__ d4,
                            const float* __restrict__ s5, ushort* __restrict__ d5) {
  int i = blockIdx.x * 256 + threadIdx.x;
  if (i < 589824) { d0[i] = f2bf(s0[i]); return; }
  i -= 589824;
  if (i < 196608) { d1[i] = f2bf(s1[i]); return; }
  i -= 196608;
  if (i < 393216) { d2[i] = f2bf(s2[i]); return; }
  i -= 393216;
  if (i < 393216) { d3[i] = f2bf(s3[i]); return; }
  i -= 393216;
  if (i < 262144) { d4[i] = f2bf(s4[i]); return; }
  i -= 262144;
  if (i < 65536) d5[i] = f2bf(s5[i]);
}

// ---------------- part encoder ----------------
__global__ void part_encoder(const float* __restrict__ parts, const float* __restrict__ Wpe1,
                             const float* __restrict__ bpe1, const float* __restrict__ Wpe2,
                             const float* __restrict__ bpe2, const float* __restrict__ pos,
                             float* __restrict__ x, ushort* __restrict__ xb) {
  __shared__ float prow[16];
  __shared__ float pe1[128];
  int row = blockIdx.x;
  int s = row & 255;
  int tid = threadIdx.x;  // 128
  if (tid < 16) prow[tid] = parts[row * 16 + tid];
  __syncthreads();
  float a = bpe1[tid];
#pragma unroll
  for (int k = 0; k < 16; ++k) a = fmaf(prow[k], Wpe1[tid * 16 + k], a);
  pe1[tid] = fmaxf(a, 0.0f);
  __syncthreads();
  float a2 = bpe2[tid];
  for (int k = 0; k < 128; ++k) a2 = fmaf(pe1[k], Wpe2[tid * 128 + k], a2);
  x[(size_t)row * 256 + tid] = a2;
  xb[(size_t)row * 256 + tid] = f2bf(a2);
  if (tid < 64) {
    float p = pos[s * 64 + tid];
    x[(size_t)row * 256 + 128 + tid] = p;
    xb[(size_t)row * 256 + 128 + tid] = f2bf(p);
    x[(size_t)row * 256 + 192 + tid] = 0.0f;
    xb[(size_t)row * 256 + 192 + tid] = 0;
  }
}

// ---------------- MFMA bf16 GEMM ----------------
// OUT: 0 = f32 C[m][n]; 1 = bf16 C[m][n]; 3 = f32 TRANSPOSED penT[(b*256+n)*256 + m%256]
template <int ACT, int OUT>
__global__ __launch_bounds__(256) void gemm_bf16(
    const ushort* __restrict__ A, const ushort* __restrict__ Wt,
    const float* __restrict__ bias1, const float* __restrict__ bias2,
    void* __restrict__ Cout, int N, int K) {
  int wid = threadIdx.x >> 6;
  int lane = threadIdx.x & 63;
  int m0 = blockIdx.y * 64 + wid * 16;
  int n0 = blockIdx.x * 64;
  int r15 = lane & 15;
  int kg = lane >> 4;
  f32x4 acc0 = {0.f, 0.f, 0.f, 0.f}, acc1 = acc0, acc2 = acc0, acc3 = acc0;
  const ushort* arow = A + (size_t)(m0 + r15) * K + kg * 8;
  const ushort* w0 = Wt + (size_t)(n0 + r15) * K + kg * 8;
  const ushort* w1 = w0 + (size_t)16 * K;
  const ushort* w2 = w0 + (size_t)32 * K;
  const ushort* w3 = w0 + (size_t)48 * K;
  for (int k0 = 0; k0 < K; k0 += 32) {
    bf16x8 af = *(const bf16x8*)(arow + k0);
    bf16x8 b0 = *(const bf16x8*)(w0 + k0);
    bf16x8 b1 = *(const bf16x8*)(w1 + k0);
    bf16x8 b2 = *(const bf16x8*)(w2 + k0);
    bf16x8 b3 = *(const bf16x8*)(w3 + k0);
    acc0 = __builtin_amdgcn_mfma_f32_16x16x32_bf16(af, b0, acc0, 0, 0, 0);
    acc1 = __builtin_amdgcn_mfma_f32_16x16x32_bf16(af, b1, acc1, 0, 0, 0);
    acc2 = __builtin_amdgcn_mfma_f32_16x16x32_bf16(af, b2, acc2, 0, 0, 0);
    acc3 = __builtin_amdgcn_mfma_f32_16x16x32_bf16(af, b3, acc3, 0, 0, 0);
  }
#pragma unroll
  for (int nn = 0; nn < 4; ++nn) {
    f32x4 a = (nn == 0) ? acc0 : (nn == 1) ? acc1 : (nn == 2) ? acc2 : acc3;
    int n = n0 + nn * 16 + r15;
    float bsum = bias1[n] + (bias2 ? bias2[n] : 0.0f);
    if (OUT == 3) {
      int b = m0 >> 8;
      int mloc = (m0 & 255) + kg * 4;
      float4 o4 = {a[0] + bsum, a[1] + bsum, a[2] + bsum, a[3] + bsum};
      *(float4*)&((float*)Cout)[((size_t)(b * 256 + n)) * 256 + mloc] = o4;
    } else {
#pragma unroll
      for (int r = 0; r < 4; ++r) {
        int m = m0 + kg * 4 + r;
        float v = a[r] + bsum;
        if (ACT == 1) v = fmaxf(v, 0.0f);
        if (OUT == 1)
          ((ushort*)Cout)[(size_t)m * N + n] = f2bf(v);
        else
          ((float*)Cout)[(size_t)m * N + n] = v;
      }
    }
  }
}

// ---------------- attention (f32 in, bf16 out) ----------------
__global__ void attn_kernel(const float* __restrict__ qkv, ushort* __restrict__ attout) {
  extern __shared__ float sm[];
  float* kl = sm;
  float* ql = sm + 256 * 33;
  float* sc = sm + 256 * 33 + 32 * 33;
  int qt = blockIdx.x, h = blockIdx.y, b = blockIdx.z;
  int tid = threadIdx.x;  // 256
  {
    int j = tid;
    const float* src = qkv + (size_t)(b * 256 + j) * 768 + 256 + h * 32;
#pragma unroll
    for (int d = 0; d < 32; d += 4) {
      float4 v = *(const float4*)(src + d);
      kl[j * 33 + d] = v.x; kl[j * 33 + d + 1] = v.y; kl[j * 33 + d + 2] = v.z; kl[j * 33 + d + 3] = v.w;
    }
  }
  {
    int i = tid >> 3, d4 = (tid & 7) * 4;
    const float* src = qkv + (size_t)(b * 256 + qt * 32 + i) * 768 + h * 32;
    float4 v = *(const float4*)(src + d4);
    ql[i * 33 + d4] = v.x; ql[i * 33 + d4 + 1] = v.y; ql[i * 33 + d4 + 2] = v.z; ql[i * 33 + d4 + 3] = v.w;
  }
  __syncthreads();
  int i = tid >> 3, c = tid & 7;
  const float scale = 0.17677669529663687f;
  float sv[32];
  float mx = -1e30f;
  for (int jj = 0; jj < 32; ++jj) {
    int j = jj * 8 + c;
    float s = 0.0f;
#pragma unroll
    for (int d = 0; d < 32; ++d) s = fmaf(ql[i * 33 + d], kl[j * 33 + d], s);
    s *= scale;
    sv[jj] = s;
    mx = fmaxf(mx, s);
  }
  mx = fmaxf(mx, __shfl_xor(mx, 1));
  mx = fmaxf(mx, __shfl_xor(mx, 2));
  mx = fmaxf(mx, __shfl_xor(mx, 4));
  float sum = 0.0f;
  for (int jj = 0; jj < 32; ++jj) {
    float p = __expf(sv[jj] - mx);
    sc[i * 257 + jj * 8 + c] = p;
    sum += p;
  }
  sum += __shfl_xor(sum, 1);
  sum += __shfl_xor(sum, 2);
  sum += __shfl_xor(sum, 4);
  float inv = 1.0f / sum;
  __syncthreads();
  float a0 = 0, a1 = 0, a2 = 0, a3 = 0;
  int d0 = c * 4;
  const float* vbase = qkv + 512 + h * 32 + d0;
  for (int j = 0; j < 256; ++j) {
    float p = sc[i * 257 + j];
    float4 v = *(const float4*)(vbase + (size_t)(b * 256 + j) * 768);
    a0 = fmaf(p, v.x, a0); a1 = fmaf(p, v.y, a1); a2 = fmaf(p, v.z, a2); a3 = fmaf(p, v.w, a3);
  }
  int orow = b * 256 + qt * 32 + i;
  ushort4 o4;
  o4.x = f2bf(a0 * inv); o4.y = f2bf(a1 * inv); o4.z = f2bf(a2 * inv); o4.w = f2bf(a3 * inv);
  *(ushort4*)&attout[(size_t)orow * 256 + h * 32 + d0] = o4;
}

// ---------------- LayerNorm(x + o) ----------------
__global__ void ln_residual(float* __restrict__ x, const float* __restrict__ o,
                            const float* __restrict__ g, const float* __restrict__ bt,
                            ushort* __restrict__ xb) {
  int row = blockIdx.x, tid = threadIdx.x;  // 256
  float e = x[(size_t)row * 256 + tid] + o[(size_t)row * 256 + tid];
  float s = e, q = e * e;
#pragma unroll
  for (int off = 32; off >= 1; off >>= 1) {
    s += __shfl_xor(s, off);
    q += __shfl_xor(q, off);
  }
  __shared__ float ps[4], pq[4];
  int wid = tid >> 6, lane = tid & 63;
  if (lane == 0) { ps[wid] = s; pq[wid] = q; }
  __syncthreads();
  float St = ps[0] + ps[1] + ps[2] + ps[3];
  float Qt = pq[0] + pq[1] + pq[2] + pq[3];
  float mean = St * (1.0f / 256.0f);
  float var = Qt * (1.0f / 256.0f) - mean * mean;
  float y = (e - mean) * rsqrtf(var + 1e-5f) * g[tid] + bt[tid];
  x[(size_t)row * 256 + tid] = y;
  xb[(size_t)row * 256 + tid] = f2bf(y);
}

// ---------------- gather dec_in ----------------
__global__ void gather_dec_in(const ushort* __restrict__ encb, const int* __restrict__ ts,
                              ushort* __restrict__ dec_in) {
  int bx = blockIdx.x;
  int t = bx >> 3, b = bx & 7;
  int tid = threadIdx.x;  // 64
  ushort4 v = {0, 0, 0, 0};
  if (t > 0) {
    int sidx = ts[b * 256 + t - 1];
    v = *(const ushort4*)&encb[((size_t)(b * 256 + sidx)) * 256 + tid * 4];
  }
  *(ushort4*)&dec_in[(size_t)bx * 256 + tid * 4] = v;
}

// ---------------- LSTM scan INT8: zero streaming, zero spill ------------------
// Whh quantized per-row to int8 (scale = rowmax/127): 256 KB total fits on-CU.
// 512 thr, R6 pairing: t0=2u+p, p0 rows (i:u, g:u+512), p1 rows (f:u+256, o:u+768).
// Per row: cols 0..175 packed int8 in regs (44 u32 x 2 rows = 88 <= 128 grant);
// cols 176..255 in LDS uint4[5][1024] (80 KB). h quantized to int8 each step:
// h8[2][64] u32 in LDS, read broadcast. Dot via v_dot4_i32_i8 (exact int accum).
// h-pack: odd lanes compute their byte, 2 shfl_xor ORs (parity-preserving,
// odd lanes only exchange with odd lanes), one writer per word. 1 barrier/step.
// dec_out written from UNQUANTIZED f32 h (quantization only in recurrence).
__global__ __attribute__((amdgpu_flat_work_group_size(512, 512)))
void lstm_scan_i8(const float* __restrict__ Xw, const float* __restrict__ Whh,
                  ushort* __restrict__ dec_out) {
#if HAVE_SDOT4
  extern __shared__ char smem[];
  unsigned int* w8l = (unsigned int*)smem;           // u32[5*4096] = 80 KB
  unsigned int* h8 = (unsigned int*)(smem + 81920);  // u32[2][64]
  const uint4* w8v = (const uint4*)smem;             // uint4[5*1024]
  int b = blockIdx.x;
  int t0 = threadIdx.x;
  int u = t0 >> 1, p = t0 & 1;
  int rA = u + 256 * p;        // i (p0) / f (p1)
  int rB = u + 512 + 256 * p;  // g (p0) / o (p1)

  unsigned int wA[44], wB[44];
  float srA, srB;
#define QROW(WARR, SR, R)                                                      \
  {                                                                            \
    const float4* s4_ = (const float4*)(Whh + (size_t)(R) * 256);              \
    float mx_ = 1e-20f;                                                        \
    for (int j = 0; j < 64; ++j) {                                             \
      float4 v = s4_[j];                                                       \
      mx_ = fmaxf(mx_, fmaxf(fmaxf(fabsf(v.x), fabsf(v.y)),                    \
                             fmaxf(fabsf(v.z), fabsf(v.w))));                  \
    }                                                                          \
    float inv_ = 127.0f / mx_;                                                 \
    SR = mx_ * (1.0f / 16129.0f);                                              \
    _Pragma("unroll") for (int j = 0; j < 64; ++j) {                           \
      float4 v = s4_[j];                                                       \
      unsigned int b0_ = (unsigned int)((int)rintf(v.x * inv_)) & 255u;        \
      unsigned int b1_ = (unsigned int)((int)rintf(v.y * inv_)) & 255u;        \
      unsigned int b2_ = (unsigned int)((int)rintf(v.z * inv_)) & 255u;        \
      unsigned int b3_ = (unsigned int)((int)rintf(v.w * inv_)) & 255u;        \
      unsigned int word_ = b0_ | (b1_ << 8) | (b2_ << 16) | (b3_ << 24);       \
      if (j < 44) WARR[j] = word_;                                             \
      else {                                                                   \
        int jj_ = j - 44;                                                      \
        w8l[(jj_ >> 2) * 4096 + (R) * 4 + (jj_ & 3)] = word_;                  \
      }                                                                        \
    }                                                                          \
  }
  QROW(wA, srA, rA)
  QROW(wB, srB, rB)
#undef QROW
  if (t0 < 128) h8[t0] = 0u;   // both parity buffers = h0 = 0
  float c = 0.0f;
  float xnA = Xw[(size_t)b * 1024 + rA];
  float xnB = Xw[(size_t)b * 1024 + rB];
  __syncthreads();

  for (int t = 0; t < 256; ++t) {
    float xwA = xnA, xwB = xnB;
    if (t < 255) {
      const float* xp = Xw + (size_t)((t + 1) * 8 + b) * 1024;
      xnA = xp[rA]; xnB = xp[rB];
    }
    const uint4* hq = (const uint4*)(h8 + (t & 1) * 64);
    int aA0 = 0, aA1 = 0, aA2 = 0, aA3 = 0;
    int aB0 = 0, aB1 = 0, aB2 = 0, aB3 = 0;
#pragma unroll
    for (int jg = 0; jg < 11; ++jg) {   // cols 0..175 from registers
      uint4 h4 = hq[jg];
      aA0 = __builtin_amdgcn_sdot4(wA[4 * jg + 0], h4.x, aA0, false);
      aA1 = __builtin_amdgcn_sdot4(wA[4 * jg + 1], h4.y, aA1, false);
      aA2 = __builtin_amdgcn_sdot4(wA[4 * jg + 2], h4.z, aA2, false);
      aA3 = __builtin_amdgcn_sdot4(wA[4 * jg + 3], h4.w, aA3, false);
      aB0 = __builtin_amdgcn_sdot4(wB[4 * jg + 0], h4.x, aB0, false);
      aB1 = __builtin_amdgcn_sdot4(wB[4 * jg + 1], h4.y, aB1, false);
      aB2 = __builtin_amdgcn_sdot4(wB[4 * jg + 2], h4.z, aB2, false);
      aB3 = __builtin_amdgcn_sdot4(wB[4 * jg + 3], h4.w, aB3, false);
    }
#pragma unroll
    for (int g = 0; g < 5; ++g) {       // cols 176..255 from LDS
      uint4 h4 = hq[11 + g];
      uint4 a4 = w8v[g * 1024 + rA];
      uint4 b4 = w8v[g * 1024 + rB];
      aA0 = __builtin_amdgcn_sdot4(a4.x, h4.x, aA0, false);
      aA1 = __builtin_amdgcn_sdot4(a4.y, h4.y, aA1, false);
      aA2 = __builtin_amdgcn_sdot4(a4.z, h4.z, aA2, false);
      aA3 = __builtin_amdgcn_sdot4(a4.w, h4.w, aA3, false);
      aB0 = __builtin_amdgcn_sdot4(b4.x, h4.x, aB0, false);
      aB1 = __builtin_amdgcn_sdot4(b4.y, h4.y, aB1, false);
      aB2 = __builtin_amdgcn_sdot4(b4.z, h4.z, aB2, false);
      aB3 = __builtin_amdgcn_sdot4(b4.w, h4.w, aB3, false);
    }
    float gA = (float)((aA0 + aA1) + (aA2 + aA3)) * srA + xwA;
    float gB = (float)((aB0 + aB1) + (aB2 + aB3)) * srB + xwB;
    float ev = sigf(gA) * tanhfast(gB);   // p0: sig(i)*tanh(g)
    float ep = __shfl_xor(ev, 1);
    float cn = sigf(gA) * c + ep;         // valid on p1 (c held by p1)
    float hv_ = sigf(gB) * tanhfast(cn);  // valid on p1
    if (p == 1) {
      c = cn;
      dec_out[((size_t)(b * 256 + t)) * 256 + u] = f2bf(hv_);
    }
    // pack h->int8: odd lanes carry real values; parity-preserving OR-combine
    int iv = (int)rintf(hv_ * 127.0f);
    unsigned int word = ((unsigned int)iv & 255u) << (8 * (u & 3));
    word |= (unsigned int)__shfl_xor((int)word, 2);
    word |= (unsigned int)__shfl_xor((int)word, 4);
    if (p == 1 && (u & 3) == 0) h8[((t + 1) & 1) * 64 + (u >> 2)] = word;
    __syncthreads();
  }
#endif
}

// ---------------- LSTM scan v512: PROVEN fallback (R6: 479 us) ----------------
__global__ __attribute__((amdgpu_flat_work_group_size(512, 512), amdgpu_waves_per_eu(1, 1)))
void lstm_scan512(const float* __restrict__ Xw, const float* __restrict__ Whh,
                  ushort* __restrict__ dec_out) {
  extern __shared__ char smem[];
  uint4* wlds = (uint4*)smem;                 // [8][1024] uint4 = 128 KB
  h2* hbuf = (h2*)(smem + 131072);            // [2][128] h2
  int b = blockIdx.x;
  int t0 = threadIdx.x;        // 0..511
  int u = t0 >> 1, p = t0 & 1;
  int rA = u + 256 * p;
  int rB = u + 512 + 256 * p;

  h2 w0[96], w1[96];
  {
    const float4* sA = (const float4*)(Whh + (size_t)rA * 256);
    const float4* sB = (const float4*)(Whh + (size_t)rB * 256);
#pragma unroll
    for (int k = 0; k < 48; ++k) {
      float4 v = sA[k];
      w0[2 * k] = cvt2(v.x, v.y);
      w0[2 * k + 1] = cvt2(v.z, v.w);
    }
#pragma unroll
    for (int k = 0; k < 48; ++k) {
      float4 v = sB[k];
      w1[2 * k] = cvt2(v.x, v.y);
      w1[2 * k + 1] = cvt2(v.z, v.w);
    }
#pragma unroll
    for (int qc = 0; qc < 8; ++qc) {
      float4 vA0 = sA[48 + 2 * qc], vA1 = sA[48 + 2 * qc + 1];
      float4 vB0 = sB[48 + 2 * qc], vB1 = sB[48 + 2 * qc + 1];
      uint4 uA, uB;
      uA.x = bcu(cvt2(vA0.x, vA0.y)); uA.y = bcu(cvt2(vA0.z, vA0.w));
      uA.z = bcu(cvt2(vA1.x, vA1.y)); uA.w = bcu(cvt2(vA1.z, vA1.w));
      uB.x = bcu(cvt2(vB0.x, vB0.y)); uB.y = bcu(cvt2(vB0.z, vB0.w));
      uB.z = bcu(cvt2(vB1.x, vB1.y)); uB.w = bcu(cvt2(vB1.z, vB1.w));
      wlds[qc * 1024 + rA] = uA;
      wlds[qc * 1024 + rB] = uB;
    }
  }
  if (t0 < 128) ((uint4*)hbuf)[t0 & 63] = make_uint4(0, 0, 0, 0);
  float c = 0.0f;
  float xnA = Xw[(size_t)b * 1024 + rA];
  float xnB = Xw[(size_t)b * 1024 + rB];
  __syncthreads();

  for (int t = 0; t < 256; ++t) {
    float xwA = xnA, xwB = xnB;
    if (t < 255) {
      const float* xp = Xw + (size_t)((t + 1) * 8 + b) * 1024;
      xnA = xp[rA]; xnB = xp[rB];
    }
    const uint4* hb = (const uint4*)(hbuf + (size_t)(t & 1) * 128);
    float a0 = 0.0f, a1 = 0.0f;
#pragma unroll
    for (int q = 0; q < 24; ++q) {
      uint4 hv = hb[q];
      h2 hx = bch2(hv.x), hy = bch2(hv.y), hz = bch2(hv.z), hw = bch2(hv.w);
      a0 = fdot2f(w0[4 * q], hx, a0); a0 = fdot2f(w0[4 * q + 1], hy, a0);
      a0 = fdot2f(w0[4 * q + 2], hz, a0); a0 = fdot2f(w0[4 * q + 3], hw, a0);
      a1 = fdot2f(w1[4 * q], hx, a1); a1 = fdot2f(w1[4 * q + 1], hy, a1);
      a1 = fdot2f(w1[4 * q + 2], hz, a1); a1 = fdot2f(w1[4 * q + 3], hw, a1);
    }
#pragma unroll
    for (int qc = 0; qc < 8; ++qc) {
      uint4 hv = hb[24 + qc];
      h2 hx = bch2(hv.x), hy = bch2(hv.y), hz = bch2(hv.z), hw = bch2(hv.w);
      uint4 uA = wlds[qc * 1024 + rA];
      uint4 uB = wlds[qc * 1024 + rB];
      a0 = fdot2f(bch2(uA.x), hx, a0); a0 = fdot2f(bch2(uA.y), hy, a0);
      a0 = fdot2f(bch2(uA.z), hz, a0); a0 = fdot2f(bch2(uA.w), hw, a0);
      a1 = fdot2f(bch2(uB.x), hx, a1); a1 = fdot2f(bch2(uB.y), hy, a1);
      a1 = fdot2f(bch2(uB.z), hz, a1); a1 = fdot2f(bch2(uB.w), hw, a1);
    }
    a0 += xwA;
    a1 += xwB;
    float ev = sigf(a0) * tanhfast(a1);
    float ep = __shfl_xor(ev, 1);
    if (p == 1) {
      c = sigf(a0) * c + ep;
      float hv_ = sigf(a1) * tanhfast(c);
      ((_Float16*)(hbuf + (size_t)((t + 1) & 1) * 128))[u] = (_Float16)hv_;
      dec_out[((size_t)(b * 256 + t)) * 256 + u] = f2bf(hv_);
    }
    __syncthreads();
  }
}

// ---------------- pointer logits ----------------
__global__ void pointer_kernel(const float* __restrict__ pd, const float* __restrict__ penT,
                               const float* __restrict__ vptr, float* __restrict__ out) {
  __shared__ float pdr[256];
  __shared__ float vl[256];
  int bx = blockIdx.x;
  int b = bx >> 8;
  int tid = threadIdx.x;  // 256
  pdr[tid] = pd[(size_t)bx * 256 + tid];
  vl[tid] = vptr[tid];
  __syncthreads();
  const float* pT = penT + (size_t)b * 256 * 256;
  float acc = 0.0f;
  for (int h = 0; h < 256; ++h) {
    acc = fmaf(vl[h], tanhfast(pdr[h] + pT[(size_t)h * 256 + tid]), acc);
  }
  out[(size_t)bx * 256 + tid] = acc;
}

extern "C" void kernel_launch(void* const* d_in, const int* in_sizes, int n_in,
                              void* d_out, int out_size, void* d_ws, size_t ws_size,
                              hipStream_t stream) {
  const float* parts = (const float*)d_in[0];
  const int* ts = (const int*)d_in[1];
  const float* Wpe1 = (const float*)d_in[2];
  const float* bpe1 = (const float*)d_in[3];
  const float* Wpe2 = (const float*)d_in[4];
  const float* bpe2 = (const float*)d_in[5];
  const float* pos = (const float*)d_in[6];
  const float* Wqkv = (const float*)d_in[7];
  const float* bqkv = (const float*)d_in[8];
  const float* Wo = (const float*)d_in[9];
  const float* bo = (const float*)d_in[10];
  const float* ln1g = (const float*)d_in[11];
  const float* ln1b = (const float*)d_in[12];
  const float* W1f = (const float*)d_in[13];
  const float* b1f = (const float*)d_in[14];
  const float* W2f = (const float*)d_in[15];
  const float* b2f = (const float*)d_in[16];
  const float* ln2g = (const float*)d_in[17];
  const float* ln2b = (const float*)d_in[18];
  const float* Wih = (const float*)d_in[19];
  const float* Whh = (const float*)d_in[20];
  const float* bih = (const float*)d_in[21];
  const float* bhh = (const float*)d_in[22];
  const float* Wp = (const float*)d_in[23];
  const float* bp = (const float*)d_in[24];
  const float* vptr = (const float*)d_in[25];
  float* out = (float*)d_out;

  // ---- workspace layout (f32-slot units) ----
  float* W = (float*)d_ws;
  float* xbuf = W;                            // [2048,256] f32, live all
  ushort* xbf = (ushort*)(W + 524288);        // [2048,256] bf16, live all
  float* SCR = W + 786432;                    // 2097152 slots scratch
  float* qkvb = SCR;                          //   encoder: [2048,768] f32
  float* obuf = SCR + 1572864;                //   encoder: [2048,256] f32
  float* Xw = SCR;                            //   decoder: [2048,1024] f32
  float* pdb = SCR;                           //   tail: [2048,256] f32
  float* penTb = SCR + 1048576;               //   tail: [8,256,256] f32 transposed
  ushort* attbf = (ushort*)(W + 2883584);     // [2048,256] bf16 (encoder)
  ushort* ffbf = (ushort*)(W + 3145728);      // [2048,512] bf16 (encoder)
  ushort* dec_inbf = (ushort*)(W + 3145728);  //   decoder: [2048,256] bf16
  ushort* dec_outbf = (ushort*)(W + 3407872); //   decoder: [2048,256] bf16
  ushort* wqkvbf = (ushort*)(W + 3670016);    // 589824 bf16
  ushort* wobf   = (ushort*)(W + 3964928);    // 196608
  ushort* w1fbf  = (ushort*)(W + 4063232);    // 393216
  ushort* w2fbf  = (ushort*)(W + 4259840);    // 393216
  ushort* wihbf  = (ushort*)(W + 4456448);    // 262144
  ushort* wpbf   = (ushort*)(W + 4587520);    // 65536

  const int attnLDS = (256 * 33 + 32 * 33 + 32 * 257) * 4;  // 70912 B
  const int scan512LDS = 131072 + 1024;                     // 132096 B
  const int scanI8LDS = 81920 + 512;                        // 82432 B
  hipFuncSetAttribute((const void*)attn_kernel, hipFuncAttributeMaxDynamicSharedMemorySize, attnLDS);
#if HAVE_SDOT4
  hipFuncSetAttribute((const void*)lstm_scan_i8, hipFuncAttributeMaxDynamicSharedMemorySize, scanI8LDS);
#else
  hipFuncSetAttribute((const void*)lstm_scan512, hipFuncAttributeMaxDynamicSharedMemorySize, scan512LDS);
#endif

  // fused weight conversion (1 launch instead of 6)
  convert_all<<<7424, 256, 0, stream>>>(Wqkv, wqkvbf, Wo, wobf, W1f, w1fbf,
                                        W2f, w2fbf, Wih, wihbf, Wp, wpbf);

  part_encoder<<<2048, 128, 0, stream>>>(parts, Wpe1, bpe1, Wpe2, bpe2, pos, xbuf, xbf);
  for (int l = 0; l < 3; ++l) {
    gemm_bf16<0, 0><<<dim3(12, 32), 256, 0, stream>>>(xbf, wqkvbf + (size_t)l * 196608,
                                                      bqkv + l * 768, nullptr, qkvb, 768, 256);
    attn_kernel<<<dim3(8, 8, 8), 256, attnLDS, stream>>>(qkvb, attbf);
    gemm_bf16<0, 0><<<dim3(4, 32), 256, 0, stream>>>(attbf, wobf + (size_t)l * 65536,
                                                     bo + l * 256, nullptr, obuf, 256, 256);
    ln_residual<<<2048, 256, 0, stream>>>(xbuf, obuf, ln1g + l * 256, ln1b + l * 256, xbf);
    gemm_bf16<1, 1><<<dim3(8, 32), 256, 0, stream>>>(xbf, w1fbf + (size_t)l * 131072,
                                                     b1f + l * 512, nullptr, ffbf, 512, 256);
    gemm_bf16<0, 0><<<dim3(4, 32), 256, 0, stream>>>(ffbf, w2fbf + (size_t)l * 131072,
                                                     b2f + l * 256, nullptr, obuf, 256, 512);
    ln_residual<<<2048, 256, 0, stream>>>(xbuf, obuf, ln2g + l * 256, ln2b + l * 256, xbf);
  }
  gather_dec_in<<<2048, 64, 0, stream>>>(xbf, ts, dec_inbf);
  gemm_bf16<0, 0><<<dim3(16, 32), 256, 0, stream>>>(dec_inbf, wihbf, bih, bhh, Xw, 1024, 256);
#if HAVE_SDOT4
  lstm_scan_i8<<<8, 512, scanI8LDS, stream>>>(Xw, Whh, dec_outbf);
#else
  lstm_scan512<<<8, 512, scan512LDS, stream>>>(Xw, Whh, dec_outbf);
#endif
  gemm_bf16<0, 0><<<dim3(4, 32), 256, 0, stream>>>(dec_outbf, wpbf, bp, nullptr, pdb, 256, 256);
  gemm_bf16<0, 3><<<dim3(4, 32), 256, 0, stream>>>(xbf, wpbf, bp, nullptr, penTb, 256, 256);
  pointer_kernel<<<2048, 256, 0, stream>>>(pdb, penTb, vptr, out);
}

// Round 14
// 848.509 us; speedup vs baseline: 1.7722x; 1.0007x over previous
//
#include <hip/hip_runtime.h>
#include <cstdint>
#include <cstddef>

typedef _Float16 h2 __attribute__((ext_vector_type(2)));
typedef short bf16x8 __attribute__((ext_vector_type(8)));
typedef float f32x4 __attribute__((ext_vector_type(4)));

#if __has_builtin(__builtin_amdgcn_mfma_f32_16x16x32_fp8_fp8)
#define HAVE_FP8MFMA 1
#else
#define HAVE_FP8MFMA 0
#endif

__device__ __forceinline__ float sigf(float x) { return 1.0f / (1.0f + __expf(-x)); }
__device__ __forceinline__ float tanhfast(float x) {
  float e = __expf(-2.0f * fabsf(x));
  float t = (1.0f - e) / (1.0f + e);
  return copysignf(t, x);
}
__device__ __forceinline__ h2 cvt2(float a, float b) {
  h2 r; r.x = (_Float16)a; r.y = (_Float16)b; return r;
}
__device__ __forceinline__ h2 bch2(unsigned int u) { return __builtin_bit_cast(h2, u); }
__device__ __forceinline__ unsigned int bcu(h2 v) { return __builtin_bit_cast(unsigned int, v); }
__device__ __forceinline__ unsigned short f2bf(float f) {
  unsigned int u = __float_as_uint(f);
  u = (u + 0x7fffu + ((u >> 16) & 1u)) >> 16;
  return (unsigned short)u;
}

__device__ __forceinline__ float fdot2f(h2 a, h2 b, float c) {
#if __has_builtin(__builtin_amdgcn_fdot2)
  return __builtin_amdgcn_fdot2(a, b, c, false);
#else
  return fmaf((float)a.x, (float)b.x, fmaf((float)a.y, (float)b.y, c));
#endif
}

// manual f32 -> OCP e4m3fn encode (RNE, flush subnormals to 0, clamp to 448)
__device__ __forceinline__ unsigned int f2fp8(float x) {
  unsigned int s = (__float_as_uint(x) & 0x80000000u) >> 24;  // sign -> bit 7
  float ax = fabsf(x);
  if (!(ax >= 0.015625f)) return s;     // below min normal 2^-6: flush (inputs pre-scaled)
  if (ax > 448.0f) ax = 448.0f;
  unsigned int u = __float_as_uint(ax);
  u += 0x7FFFFu + ((u >> 20) & 1u);     // RNE to 3-bit mantissa (drop 20 bits)
  int e4 = (int)(u >> 23) - 120;        // -127 + 7 rebias
  unsigned int m3 = (u >> 20) & 7u;
  if (e4 > 15) { e4 = 15; m3 = 6u; }    // clamp to 448 (avoid 0x7F = NaN)
  return s | ((unsigned int)e4 << 3) | m3;
}

// ---------------- fused f32 -> bf16 convert for ALL weights (1 launch) ---------
__global__ void convert_all(const float* __restrict__ s0, ushort* __restrict__ d0,
                            const float* __restrict__ s1, ushort* __restrict__ d1,
                            const float* __restrict__ s2, ushort* __restrict__ d2,
                            const float* __restrict__ s3, ushort* __restrict__ d3,
                            const float* __restrict__ s4, ushort* __restrict__ d4,
                            const float* __restrict__ s5, ushort* __restrict__ d5) {
  int i = blockIdx.x * 256 + threadIdx.x;
  if (i < 589824) { d0[i] = f2bf(s0[i]); return; }
  i -= 589824;
  if (i < 196608) { d1[i] = f2bf(s1[i]); return; }
  i -= 196608;
  if (i < 393216) { d2[i] = f2bf(s2[i]); return; }
  i -= 393216;
  if (i < 393216) { d3[i] = f2bf(s3[i]); return; }
  i -= 393216;
  if (i < 262144) { d4[i] = f2bf(s4[i]); return; }
  i -= 262144;
  if (i < 65536) d5[i] = f2bf(s5[i]);
}

// ---------------- Whh f32 -> fp8 e4m3 with per-row scale ----------------
// 1024 blocks (one per gate-row) x 256 threads. rsc[row] = rowmax/57600
// (gate = acc * rowmax/240 * 1/240, h pre-scaled by 240).
__global__ void quant_whh(const float* __restrict__ Whh, unsigned char* __restrict__ W8,
                          float* __restrict__ rsc) {
  __shared__ float wmx[4];
  int row = blockIdx.x, tid = threadIdx.x;
  float v = Whh[(size_t)row * 256 + tid];
  float mx = fabsf(v);
#pragma unroll
  for (int off = 32; off >= 1; off >>= 1) mx = fmaxf(mx, __shfl_xor(mx, off));
  if ((tid & 63) == 0) wmx[tid >> 6] = mx;
  __syncthreads();
  float rowmax = fmaxf(fmaxf(wmx[0], wmx[1]), fmaxf(wmx[2], wmx[3]));
  rowmax = fmaxf(rowmax, 1e-8f);
  float scale = 240.0f / rowmax;
  W8[(size_t)row * 256 + tid] = (unsigned char)f2fp8(v * scale);
  if (tid == 0) rsc[row] = rowmax * (1.0f / 57600.0f);
}

// ---------------- part encoder ----------------
__global__ void part_encoder(const float* __restrict__ parts, const float* __restrict__ Wpe1,
                             const float* __restrict__ bpe1, const float* __restrict__ Wpe2,
                             const float* __restrict__ bpe2, const float* __restrict__ pos,
                             float* __restrict__ x, ushort* __restrict__ xb) {
  __shared__ float prow[16];
  __shared__ float pe1[128];
  int row = blockIdx.x;
  int s = row & 255;
  int tid = threadIdx.x;  // 128
  if (tid < 16) prow[tid] = parts[row * 16 + tid];
  __syncthreads();
  float a = bpe1[tid];
#pragma unroll
  for (int k = 0; k < 16; ++k) a = fmaf(prow[k], Wpe1[tid * 16 + k], a);
  pe1[tid] = fmaxf(a, 0.0f);
  __syncthreads();
  float a2 = bpe2[tid];
  for (int k = 0; k < 128; ++k) a2 = fmaf(pe1[k], Wpe2[tid * 128 + k], a2);
  x[(size_t)row * 256 + tid] = a2;
  xb[(size_t)row * 256 + tid] = f2bf(a2);
  if (tid < 64) {
    float p = pos[s * 64 + tid];
    x[(size_t)row * 256 + 128 + tid] = p;
    xb[(size_t)row * 256 + 128 + tid] = f2bf(p);
    x[(size_t)row * 256 + 192 + tid] = 0.0f;
    xb[(size_t)row * 256 + 192 + tid] = 0;
  }
}

// ---------------- MFMA bf16 GEMM ----------------
// OUT: 0 = f32 C[m][n]; 1 = bf16 C[m][n]; 3 = f32 TRANSPOSED penT[(b*256+n)*256 + m%256]
template <int ACT, int OUT>
__global__ __launch_bounds__(256) void gemm_bf16(
    const ushort* __restrict__ A, const ushort* __restrict__ Wt,
    const float* __restrict__ bias1, const float* __restrict__ bias2,
    void* __restrict__ Cout, int N, int K) {
  int wid = threadIdx.x >> 6;
  int lane = threadIdx.x & 63;
  int m0 = blockIdx.y * 64 + wid * 16;
  int n0 = blockIdx.x * 64;
  int r15 = lane & 15;
  int kg = lane >> 4;
  f32x4 acc0 = {0.f, 0.f, 0.f, 0.f}, acc1 = acc0, acc2 = acc0, acc3 = acc0;
  const ushort* arow = A + (size_t)(m0 + r15) * K + kg * 8;
  const ushort* w0 = Wt + (size_t)(n0 + r15) * K + kg * 8;
  const ushort* w1 = w0 + (size_t)16 * K;
  const ushort* w2 = w0 + (size_t)32 * K;
  const ushort* w3 = w0 + (size_t)48 * K;
  for (int k0 = 0; k0 < K; k0 += 32) {
    bf16x8 af = *(const bf16x8*)(arow + k0);
    bf16x8 b0 = *(const bf16x8*)(w0 + k0);
    bf16x8 b1 = *(const bf16x8*)(w1 + k0);
    bf16x8 b2 = *(const bf16x8*)(w2 + k0);
    bf16x8 b3 = *(const bf16x8*)(w3 + k0);
    acc0 = __builtin_amdgcn_mfma_f32_16x16x32_bf16(af, b0, acc0, 0, 0, 0);
    acc1 = __builtin_amdgcn_mfma_f32_16x16x32_bf16(af, b1, acc1, 0, 0, 0);
    acc2 = __builtin_amdgcn_mfma_f32_16x16x32_bf16(af, b2, acc2, 0, 0, 0);
    acc3 = __builtin_amdgcn_mfma_f32_16x16x32_bf16(af, b3, acc3, 0, 0, 0);
  }
#pragma unroll
  for (int nn = 0; nn < 4; ++nn) {
    f32x4 a = (nn == 0) ? acc0 : (nn == 1) ? acc1 : (nn == 2) ? acc2 : acc3;
    int n = n0 + nn * 16 + r15;
    float bsum = bias1[n] + (bias2 ? bias2[n] : 0.0f);
    if (OUT == 3) {
      int b = m0 >> 8;
      int mloc = (m0 & 255) + kg * 4;
      float4 o4 = {a[0] + bsum, a[1] + bsum, a[2] + bsum, a[3] + bsum};
      *(float4*)&((float*)Cout)[((size_t)(b * 256 + n)) * 256 + mloc] = o4;
    } else {
#pragma unroll
      for (int r = 0; r < 4; ++r) {
        int m = m0 + kg * 4 + r;
        float v = a[r] + bsum;
        if (ACT == 1) v = fmaxf(v, 0.0f);
        if (OUT == 1)
          ((ushort*)Cout)[(size_t)m * N + n] = f2bf(v);
        else
          ((float*)Cout)[(size_t)m * N + n] = v;
      }
    }
  }
}

// ---------------- attention (f32 in, bf16 out) ----------------
__global__ void attn_kernel(const float* __restrict__ qkv, ushort* __restrict__ attout) {
  extern __shared__ float sm[];
  float* kl = sm;
  float* ql = sm + 256 * 33;
  float* sc = sm + 256 * 33 + 32 * 33;
  int qt = blockIdx.x, h = blockIdx.y, b = blockIdx.z;
  int tid = threadIdx.x;  // 256
  {
    int j = tid;
    const float* src = qkv + (size_t)(b * 256 + j) * 768 + 256 + h * 32;
#pragma unroll
    for (int d = 0; d < 32; d += 4) {
      float4 v = *(const float4*)(src + d);
      kl[j * 33 + d] = v.x; kl[j * 33 + d + 1] = v.y; kl[j * 33 + d + 2] = v.z; kl[j * 33 + d + 3] = v.w;
    }
  }
  {
    int i = tid >> 3, d4 = (tid & 7) * 4;
    const float* src = qkv + (size_t)(b * 256 + qt * 32 + i) * 768 + h * 32;
    float4 v = *(const float4*)(src + d4);
    ql[i * 33 + d4] = v.x; ql[i * 33 + d4 + 1] = v.y; ql[i * 33 + d4 + 2] = v.z; ql[i * 33 + d4 + 3] = v.w;
  }
  __syncthreads();
  int i = tid >> 3, c = tid & 7;
  const float scale = 0.17677669529663687f;
  float sv[32];
  float mx = -1e30f;
  for (int jj = 0; jj < 32; ++jj) {
    int j = jj * 8 + c;
    float s = 0.0f;
#pragma unroll
    for (int d = 0; d < 32; ++d) s = fmaf(ql[i * 33 + d], kl[j * 33 + d], s);
    s *= scale;
    sv[jj] = s;
    mx = fmaxf(mx, s);
  }
  mx = fmaxf(mx, __shfl_xor(mx, 1));
  mx = fmaxf(mx, __shfl_xor(mx, 2));
  mx = fmaxf(mx, __shfl_xor(mx, 4));
  float sum = 0.0f;
  for (int jj = 0; jj < 32; ++jj) {
    float p = __expf(sv[jj] - mx);
    sc[i * 257 + jj * 8 + c] = p;
    sum += p;
  }
  sum += __shfl_xor(sum, 1);
  sum += __shfl_xor(sum, 2);
  sum += __shfl_xor(sum, 4);
  float inv = 1.0f / sum;
  __syncthreads();
  float a0 = 0, a1 = 0, a2 = 0, a3 = 0;
  int d0 = c * 4;
  const float* vbase = qkv + 512 + h * 32 + d0;
  for (int j = 0; j < 256; ++j) {
    float p = sc[i * 257 + j];
    float4 v = *(const float4*)(vbase + (size_t)(b * 256 + j) * 768);
    a0 = fmaf(p, v.x, a0); a1 = fmaf(p, v.y, a1); a2 = fmaf(p, v.z, a2); a3 = fmaf(p, v.w, a3);
  }
  int orow = b * 256 + qt * 32 + i;
  ushort4 o4;
  o4.x = f2bf(a0 * inv); o4.y = f2bf(a1 * inv); o4.z = f2bf(a2 * inv); o4.w = f2bf(a3 * inv);
  *(ushort4*)&attout[(size_t)orow * 256 + h * 32 + d0] = o4;
}

// ---------------- LayerNorm(x + o) ----------------
__global__ void ln_residual(float* __restrict__ x, const float* __restrict__ o,
                            const float* __restrict__ g, const float* __restrict__ bt,
                            ushort* __restrict__ xb) {
  int row = blockIdx.x, tid = threadIdx.x;  // 256
  float e = x[(size_t)row * 256 + tid] + o[(size_t)row * 256 + tid];
  float s = e, q = e * e;
#pragma unroll
  for (int off = 32; off >= 1; off >>= 1) {
    s += __shfl_xor(s, off);
    q += __shfl_xor(q, off);
  }
  __shared__ float ps[4], pq[4];
  int wid = tid >> 6, lane = tid & 63;
  if (lane == 0) { ps[wid] = s; pq[wid] = q; }
  __syncthreads();
  float St = ps[0] + ps[1] + ps[2] + ps[3];
  float Qt = pq[0] + pq[1] + pq[2] + pq[3];
  float mean = St * (1.0f / 256.0f);
  float var = Qt * (1.0f / 256.0f) - mean * mean;
  float y = (e - mean) * rsqrtf(var + 1e-5f) * g[tid] + bt[tid];
  x[(size_t)row * 256 + tid] = y;
  xb[(size_t)row * 256 + tid] = f2bf(y);
}

// ---------------- gather dec_in ----------------
__global__ void gather_dec_in(const ushort* __restrict__ encb, const int* __restrict__ ts,
                              ushort* __restrict__ dec_in) {
  int bx = blockIdx.x;
  int t = bx >> 3, b = bx & 7;
  int tid = threadIdx.x;  // 64
  ushort4 v = {0, 0, 0, 0};
  if (t > 0) {
    int sidx = ts[b * 256 + t - 1];
    v = *(const ushort4*)&encb[((size_t)(b * 256 + sidx)) * 256 + tid * 4];
  }
  *(ushort4*)&dec_in[(size_t)bx * 256 + tid * 4] = v;
}

// ---------------- LSTM scan FP8-MFMA: 1 block/batch, 512 thr ----------------
// G[16x1024] = A(16x256) @ B(256x1024), A = h broadcast to ALL 16 rows (no
// masking; every output row equals h @ Whh^T; read any row in epilogue).
// B-frags (fp8, 2 regs = 8 bytes): per wave 8 col-tiles; tiles 0..3 REGISTER-
// resident packed fp8 (64 VGPRs = the storage, MFMA consumes fp8 directly,
// zero per-step conversion); tiles 4..7 in LDS [32wt][4kp][64lane]x16B (128 KB,
// lane-contiguous = conflict-free). h as fp8 in LDS: 256 B/parity -> only 4
// broadcast b128 A-reads per wave per step (vs 32 bf16 h reads in scan512).
// Per-row weight scales (rsc) applied in epilogue. 2 barriers/step.
__global__ __attribute__((amdgpu_flat_work_group_size(512, 512)))
void lstm_scan_fp8(const float* __restrict__ Xw, const unsigned char* __restrict__ W8,
                   const float* __restrict__ rsc, ushort* __restrict__ dec_out) {
#if HAVE_FP8MFMA
  extern __shared__ char smem[];
  uint4* ldsB = (uint4*)smem;                       // [32][4][64] uint4 = 128 KB
  uint4* h8v = (uint4*)(smem + 131072);             // [2][16] uint4 = 512 B
  unsigned char* h8b = (unsigned char*)(smem + 131072);
  float* gl = (float*)(smem + 131584);              // [1024] f32 = 4 KB
  int b = blockIdx.x;
  int t0 = threadIdx.x;
  int w = t0 >> 6, l = t0 & 63;
  int oct = l >> 4, c15 = l & 15;

  // register B-frag tiles 0..3: brg[t*8+ks] = Whh8[col][ks*32+oct*8 .. +8]
  long brg[32];
#pragma unroll
  for (int tt = 0; tt < 4; ++tt) {
    int col = w * 128 + tt * 16 + c15;
#pragma unroll
    for (int ks = 0; ks < 8; ++ks)
      brg[tt * 8 + ks] = *(const long*)(W8 + (size_t)col * 256 + ks * 32 + oct * 8);
  }
  // LDS B tiles 4..7
  for (int tt = 4; tt < 8; ++tt) {
    int col = w * 128 + tt * 16 + c15;
    int wt = w * 4 + (tt - 4);
#pragma unroll
    for (int kp = 0; kp < 4; ++kp) {
      const unsigned int* p0 = (const unsigned int*)(W8 + (size_t)col * 256 + (2 * kp) * 32 + oct * 8);
      const unsigned int* p1 = (const unsigned int*)(W8 + (size_t)col * 256 + (2 * kp + 1) * 32 + oct * 8);
      uint4 q;
      q.x = p0[0]; q.y = p0[1]; q.z = p1[0]; q.w = p1[1];
      ldsB[wt * 256 + kp * 64 + l] = q;
    }
  }
  if (t0 < 32) h8v[t0] = make_uint4(0, 0, 0, 0);  // both h parities = fp8(0)

  float c = 0.0f;
  float rs0 = 0, rs1 = 0, rs2 = 0, rs3 = 0;
  float xni = 0, xnf = 0, xng = 0, xno = 0;
  int u = t0;
  if (t0 < 256) {
    rs0 = rsc[u]; rs1 = rsc[256 + u]; rs2 = rsc[512 + u]; rs3 = rsc[768 + u];
    const float* xp = Xw + (size_t)b * 1024;
    xni = xp[u]; xnf = xp[256 + u]; xng = xp[512 + u]; xno = xp[768 + u];
  }
  // h8 byte offset for unit u: k=u -> [oct=(u&31)>>3][ks=u>>5][j=u&7]
  int hoff = ((u & 31) >> 3) * 64 + ((u >> 5) & 7) * 8 + (u & 7);
  __syncthreads();

  int cur = 0;
  for (int t = 0; t < 256; ++t) {
    float xwi = xni, xwf = xnf, xwg = xng, xwo = xno;
    if (t0 < 256 && t < 255) {
      const float* xp = Xw + (size_t)((t + 1) * 8 + b) * 1024;
      xni = xp[u]; xnf = xp[256 + u]; xng = xp[512 + u]; xno = xp[768 + u];
    }
    // A-frags: broadcast h (same bytes for all 16 rows of each oct group)
    long A0, A1, A2, A3, A4, A5, A6, A7;
    {
      uint4 qa = h8v[cur * 16 + oct * 4 + 0];
      A0 = __builtin_bit_cast(long, make_uint2(qa.x, qa.y));
      A1 = __builtin_bit_cast(long, make_uint2(qa.z, qa.w));
      qa = h8v[cur * 16 + oct * 4 + 1];
      A2 = __builtin_bit_cast(long, make_uint2(qa.x, qa.y));
      A3 = __builtin_bit_cast(long, make_uint2(qa.z, qa.w));
      qa = h8v[cur * 16 + oct * 4 + 2];
      A4 = __builtin_bit_cast(long, make_uint2(qa.x, qa.y));
      A5 = __builtin_bit_cast(long, make_uint2(qa.z, qa.w));
      qa = h8v[cur * 16 + oct * 4 + 3];
      A6 = __builtin_bit_cast(long, make_uint2(qa.x, qa.y));
      A7 = __builtin_bit_cast(long, make_uint2(qa.z, qa.w));
    }
    float gv[8];
#pragma unroll
    for (int tt = 0; tt < 4; ++tt) {
      f32x4 acc = {0.f, 0.f, 0.f, 0.f};
      acc = __builtin_amdgcn_mfma_f32_16x16x32_fp8_fp8(A0, brg[tt * 8 + 0], acc, 0, 0, 0);
      acc = __builtin_amdgcn_mfma_f32_16x16x32_fp8_fp8(A1, brg[tt * 8 + 1], acc, 0, 0, 0);
      acc = __builtin_amdgcn_mfma_f32_16x16x32_fp8_fp8(A2, brg[tt * 8 + 2], acc, 0, 0, 0);
      acc = __builtin_amdgcn_mfma_f32_16x16x32_fp8_fp8(A3, brg[tt * 8 + 3], acc, 0, 0, 0);
      acc = __builtin_amdgcn_mfma_f32_16x16x32_fp8_fp8(A4, brg[tt * 8 + 4], acc, 0, 0, 0);
      acc = __builtin_amdgcn_mfma_f32_16x16x32_fp8_fp8(A5, brg[tt * 8 + 5], acc, 0, 0, 0);
      acc = __builtin_amdgcn_mfma_f32_16x16x32_fp8_fp8(A6, brg[tt * 8 + 6], acc, 0, 0, 0);
      acc = __builtin_amdgcn_mfma_f32_16x16x32_fp8_fp8(A7, brg[tt * 8 + 7], acc, 0, 0, 0);
      gv[tt] = acc[0];
    }
#pragma unroll
    for (int tt = 4; tt < 8; ++tt) {
      int wt = w * 4 + (tt - 4);
      f32x4 acc = {0.f, 0.f, 0.f, 0.f};
#pragma unroll
      for (int kp = 0; kp < 4; ++kp) {
        uint4 q = ldsB[wt * 256 + kp * 64 + l];
        long b0 = __builtin_bit_cast(long, make_uint2(q.x, q.y));
        long b1 = __builtin_bit_cast(long, make_uint2(q.z, q.w));
        long Ae = (kp == 0) ? A0 : (kp == 1) ? A2 : (kp == 2) ? A4 : A6;
        long Ao = (kp == 0) ? A1 : (kp == 1) ? A3 : (kp == 2) ? A5 : A7;
        acc = __builtin_amdgcn_mfma_f32_16x16x32_fp8_fp8(Ae, b0, acc, 0, 0, 0);
        acc = __builtin_amdgcn_mfma_f32_16x16x32_fp8_fp8(Ao, b1, acc, 0, 0, 0);
      }
      gv[tt] = acc[0];
    }
    if (l < 16) {
#pragma unroll
      for (int tt = 0; tt < 8; ++tt) gl[w * 128 + tt * 16 + l] = gv[tt];
    }
    __syncthreads();
    if (t0 < 256) {
      float gi = gl[u] * rs0 + xwi;
      float gf = gl[256 + u] * rs1 + xwf;
      float gg = gl[512 + u] * rs2 + xwg;
      float go = gl[768 + u] * rs3 + xwo;
      c = sigf(gf) * c + sigf(gi) * tanhfast(gg);
      float hv_ = sigf(go) * tanhfast(c);
      dec_out[((size_t)(b * 256 + t)) * 256 + u] = f2bf(hv_);
      h8b[(cur ^ 1) * 256 + hoff] = (unsigned char)f2fp8(hv_ * 240.0f);
    }
    __syncthreads();
    cur ^= 1;
  }
#endif
}

// ---------------- LSTM scan v512: PROVEN fallback (R6: 479 us) ----------------
__global__ __attribute__((amdgpu_flat_work_group_size(512, 512), amdgpu_waves_per_eu(1, 1)))
void lstm_scan512(const float* __restrict__ Xw, const float* __restrict__ Whh,
                  ushort* __restrict__ dec_out) {
  extern __shared__ char smem[];
  uint4* wlds = (uint4*)smem;                 // [8][1024] uint4 = 128 KB
  h2* hbuf = (h2*)(smem + 131072);            // [2][128] h2
  int b = blockIdx.x;
  int t0 = threadIdx.x;        // 0..511
  int u = t0 >> 1, p = t0 & 1;
  int rA = u + 256 * p;
  int rB = u + 512 + 256 * p;

  h2 w0[96], w1[96];
  {
    const float4* sA = (const float4*)(Whh + (size_t)rA * 256);
    const float4* sB = (const float4*)(Whh + (size_t)rB * 256);
#pragma unroll
    for (int k = 0; k < 48; ++k) {
      float4 v = sA[k];
      w0[2 * k] = cvt2(v.x, v.y);
      w0[2 * k + 1] = cvt2(v.z, v.w);
    }
#pragma unroll
    for (int k = 0; k < 48; ++k) {
      float4 v = sB[k];
      w1[2 * k] = cvt2(v.x, v.y);
      w1[2 * k + 1] = cvt2(v.z, v.w);
    }
#pragma unroll
    for (int qc = 0; qc < 8; ++qc) {
      float4 vA0 = sA[48 + 2 * qc], vA1 = sA[48 + 2 * qc + 1];
      float4 vB0 = sB[48 + 2 * qc], vB1 = sB[48 + 2 * qc + 1];
      uint4 uA, uB;
      uA.x = bcu(cvt2(vA0.x, vA0.y)); uA.y = bcu(cvt2(vA0.z, vA0.w));
      uA.z = bcu(cvt2(vA1.x, vA1.y)); uA.w = bcu(cvt2(vA1.z, vA1.w));
      uB.x = bcu(cvt2(vB0.x, vB0.y)); uB.y = bcu(cvt2(vB0.z, vB0.w));
      uB.z = bcu(cvt2(vB1.x, vB1.y)); uB.w = bcu(cvt2(vB1.z, vB1.w));
      wlds[qc * 1024 + rA] = uA;
      wlds[qc * 1024 + rB] = uB;
    }
  }
  if (t0 < 128) ((uint4*)hbuf)[t0 & 63] = make_uint4(0, 0, 0, 0);
  float c = 0.0f;
  float xnA = Xw[(size_t)b * 1024 + rA];
  float xnB = Xw[(size_t)b * 1024 + rB];
  __syncthreads();

  for (int t = 0; t < 256; ++t) {
    float xwA = xnA, xwB = xnB;
    if (t < 255) {
      const float* xp = Xw + (size_t)((t + 1) * 8 + b) * 1024;
      xnA = xp[rA]; xnB = xp[rB];
    }
    const uint4* hb = (const uint4*)(hbuf + (size_t)(t & 1) * 128);
    float a0 = 0.0f, a1 = 0.0f;
#pragma unroll
    for (int q = 0; q < 24; ++q) {
      uint4 hv = hb[q];
      h2 hx = bch2(hv.x), hy = bch2(hv.y), hz = bch2(hv.z), hw = bch2(hv.w);
      a0 = fdot2f(w0[4 * q], hx, a0); a0 = fdot2f(w0[4 * q + 1], hy, a0);
      a0 = fdot2f(w0[4 * q + 2], hz, a0); a0 = fdot2f(w0[4 * q + 3], hw, a0);
      a1 = fdot2f(w1[4 * q], hx, a1); a1 = fdot2f(w1[4 * q + 1], hy, a1);
      a1 = fdot2f(w1[4 * q + 2], hz, a1); a1 = fdot2f(w1[4 * q + 3], hw, a1);
    }
#pragma unroll
    for (int qc = 0; qc < 8; ++qc) {
      uint4 hv = hb[24 + qc];
      h2 hx = bch2(hv.x), hy = bch2(hv.y), hz = bch2(hv.z), hw = bch2(hv.w);
      uint4 uA = wlds[qc * 1024 + rA];
      uint4 uB = wlds[qc * 1024 + rB];
      a0 = fdot2f(bch2(uA.x), hx, a0); a0 = fdot2f(bch2(uA.y), hy, a0);
      a0 = fdot2f(bch2(uA.z), hz, a0); a0 = fdot2f(bch2(uA.w), hw, a0);
      a1 = fdot2f(bch2(uB.x), hx, a1); a1 = fdot2f(bch2(uB.y), hy, a1);
      a1 = fdot2f(bch2(uB.z), hz, a1); a1 = fdot2f(bch2(uB.w), hw, a1);
    }
    a0 += xwA;
    a1 += xwB;
    float ev = sigf(a0) * tanhfast(a1);
    float ep = __shfl_xor(ev, 1);
    if (p == 1) {
      c = sigf(a0) * c + ep;
      float hv_ = sigf(a1) * tanhfast(c);
      ((_Float16*)(hbuf + (size_t)((t + 1) & 1) * 128))[u] = (_Float16)hv_;
      dec_out[((size_t)(b * 256 + t)) * 256 + u] = f2bf(hv_);
    }
    __syncthreads();
  }
}

// ---------------- pointer logits ----------------
__global__ void pointer_kernel(const float* __restrict__ pd, const float* __restrict__ penT,
                               const float* __restrict__ vptr, float* __restrict__ out) {
  __shared__ float pdr[256];
  __shared__ float vl[256];
  int bx = blockIdx.x;
  int b = bx >> 8;
  int tid = threadIdx.x;  // 256
  pdr[tid] = pd[(size_t)bx * 256 + tid];
  vl[tid] = vptr[tid];
  __syncthreads();
  const float* pT = penT + (size_t)b * 256 * 256;
  float acc = 0.0f;
  for (int h = 0; h < 256; ++h) {
    acc = fmaf(vl[h], tanhfast(pdr[h] + pT[(size_t)h * 256 + tid]), acc);
  }
  out[(size_t)bx * 256 + tid] = acc;
}

extern "C" void kernel_launch(void* const* d_in, const int* in_sizes, int n_in,
                              void* d_out, int out_size, void* d_ws, size_t ws_size,
                              hipStream_t stream) {
  const float* parts = (const float*)d_in[0];
  const int* ts = (const int*)d_in[1];
  const float* Wpe1 = (const float*)d_in[2];
  const float* bpe1 = (const float*)d_in[3];
  const float* Wpe2 = (const float*)d_in[4];
  const float* bpe2 = (const float*)d_in[5];
  const float* pos = (const float*)d_in[6];
  const float* Wqkv = (const float*)d_in[7];
  const float* bqkv = (const float*)d_in[8];
  const float* Wo = (const float*)d_in[9];
  const float* bo = (const float*)d_in[10];
  const float* ln1g = (const float*)d_in[11];
  const float* ln1b = (const float*)d_in[12];
  const float* W1f = (const float*)d_in[13];
  const float* b1f = (const float*)d_in[14];
  const float* W2f = (const float*)d_in[15];
  const float* b2f = (const float*)d_in[16];
  const float* ln2g = (const float*)d_in[17];
  const float* ln2b = (const float*)d_in[18];
  const float* Wih = (const float*)d_in[19];
  const float* Whh = (const float*)d_in[20];
  const float* bih = (const float*)d_in[21];
  const float* bhh = (const float*)d_in[22];
  const float* Wp = (const float*)d_in[23];
  const float* bp = (const float*)d_in[24];
  const float* vptr = (const float*)d_in[25];
  float* out = (float*)d_out;

  // ---- workspace layout (f32-slot units) ----
  float* W = (float*)d_ws;
  float* xbuf = W;                            // [2048,256] f32, live all
  ushort* xbf = (ushort*)(W + 524288);        // [2048,256] bf16, live all
  float* SCR = W + 786432;                    // 2097152 slots scratch
  float* qkvb = SCR;                          //   encoder: [2048,768] f32
  float* obuf = SCR + 1572864;                //   encoder: [2048,256] f32
  float* Xw = SCR;                            //   decoder: [2048,1024] f32
  float* pdb = SCR;                           //   tail: [2048,256] f32
  float* penTb = SCR + 1048576;               //   tail: [8,256,256] f32 transposed
  ushort* attbf = (ushort*)(W + 2883584);     // [2048,256] bf16 (encoder)
  ushort* ffbf = (ushort*)(W + 3145728);      // [2048,512] bf16 (encoder)
  ushort* dec_inbf = (ushort*)(W + 3145728);  //   decoder: [2048,256] bf16
  ushort* dec_outbf = (ushort*)(W + 3407872); //   decoder: [2048,256] bf16
  ushort* wqkvbf = (ushort*)(W + 3670016);    // 589824 bf16
  ushort* wobf   = (ushort*)(W + 3964928);    // 196608
  ushort* w1fbf  = (ushort*)(W + 4063232);    // 393216
  ushort* w2fbf  = (ushort*)(W + 4259840);    // 393216
  ushort* wihbf  = (ushort*)(W + 4456448);    // 262144
  ushort* wpbf   = (ushort*)(W + 4587520);    // 65536
  unsigned char* whh8 = (unsigned char*)(W + 4620288);  // 262144 B (65536 slots)
  float* rscb = W + 4685824;                  // [1024] f32

  const int attnLDS = (256 * 33 + 32 * 33 + 32 * 257) * 4;  // 70912 B
  const int scan512LDS = 131072 + 1024;                     // 132096 B
  const int scanFp8LDS = 131072 + 512 + 4096;               // 135680 B
  hipFuncSetAttribute((const void*)attn_kernel, hipFuncAttributeMaxDynamicSharedMemorySize, attnLDS);
#if HAVE_FP8MFMA
  hipFuncSetAttribute((const void*)lstm_scan_fp8, hipFuncAttributeMaxDynamicSharedMemorySize, scanFp8LDS);
#else
  hipFuncSetAttribute((const void*)lstm_scan512, hipFuncAttributeMaxDynamicSharedMemorySize, scan512LDS);
#endif

  // fused weight conversion (1 launch)
  convert_all<<<7424, 256, 0, stream>>>(Wqkv, wqkvbf, Wo, wobf, W1f, w1fbf,
                                        W2f, w2fbf, Wih, wihbf, Wp, wpbf);
#if HAVE_FP8MFMA
  quant_whh<<<1024, 256, 0, stream>>>(Whh, whh8, rscb);
#endif

  part_encoder<<<2048, 128, 0, stream>>>(parts, Wpe1, bpe1, Wpe2, bpe2, pos, xbuf, xbf);
  for (int l = 0; l < 3; ++l) {
    gemm_bf16<0, 0><<<dim3(12, 32), 256, 0, stream>>>(xbf, wqkvbf + (size_t)l * 196608,
                                                      bqkv + l * 768, nullptr, qkvb, 768, 256);
    attn_kernel<<<dim3(8, 8, 8), 256, attnLDS, stream>>>(qkvb, attbf);
    gemm_bf16<0, 0><<<dim3(4, 32), 256, 0, stream>>>(attbf, wobf + (size_t)l * 65536,
                                                     bo + l * 256, nullptr, obuf, 256, 256);
    ln_residual<<<2048, 256, 0, stream>>>(xbuf, obuf, ln1g + l * 256, ln1b + l * 256, xbf);
    gemm_bf16<1, 1><<<dim3(8, 32), 256, 0, stream>>>(xbf, w1fbf + (size_t)l * 131072,
                                                     b1f + l * 512, nullptr, ffbf, 512, 256);
    gemm_bf16<0, 0><<<dim3(4, 32), 256, 0, stream>>>(ffbf, w2fbf + (size_t)l * 131072,
                                                     b2f + l * 256, nullptr, obuf, 256, 512);
    ln_residual<<<2048, 256, 0, stream>>>(xbuf, obuf, ln2g + l * 256, ln2b + l * 256, xbf);
  }
  gather_dec_in<<<2048, 64, 0, stream>>>(xbf, ts, dec_inbf);
  gemm_bf16<0, 0><<<dim3(16, 32), 256, 0, stream>>>(dec_inbf, wihbf, bih, bhh, Xw, 1024, 256);
#if HAVE_FP8MFMA
  lstm_scan_fp8<<<8, 512, scanFp8LDS, stream>>>(Xw, whh8, rscb, dec_outbf);
#else
  lstm_scan512<<<8, 512, scan512LDS, stream>>>(Xw, Whh, dec_outbf);
#endif
  gemm_bf16<0, 0><<<dim3(4, 32), 256, 0, stream>>>(dec_outbf, wpbf, bp, nullptr, pdb, 256, 256);
  gemm_bf16<0, 3><<<dim3(4, 32), 256, 0, stream>>>(xbf, wpbf, bp, nullptr, penTb, 256, 256);
  pointer_kernel<<<2048, 256, 0, stream>>>(pdb, penTb, vptr, out);
}

// Round 15
// 825.550 us; speedup vs baseline: 1.8215x; 1.0278x over previous
//
#include <hip/hip_runtime.h>
#include <cstdint>
#include <cstddef>

// LESSON (R13/R14): __has_builtin(__builtin_amdgcn_*) is FALSE in hipcc's HOST
// pass — never use it to select kernel launches host-side. Device-verified
// builtins (bf16 MFMA, fdot2) are used unconditionally below.

typedef _Float16 h2 __attribute__((ext_vector_type(2)));
typedef short bf16x8 __attribute__((ext_vector_type(8)));
typedef float f32x4 __attribute__((ext_vector_type(4)));

__device__ __forceinline__ float sigf(float x) { return 1.0f / (1.0f + __expf(-x)); }
__device__ __forceinline__ float tanhfast(float x) {
  float e = __expf(-2.0f * fabsf(x));
  float t = (1.0f - e) / (1.0f + e);
  return copysignf(t, x);
}
__device__ __forceinline__ h2 cvt2(float a, float b) {
  h2 r; r.x = (_Float16)a; r.y = (_Float16)b; return r;
}
__device__ __forceinline__ h2 bch2(unsigned int u) { return __builtin_bit_cast(h2, u); }
__device__ __forceinline__ unsigned int bcu(h2 v) { return __builtin_bit_cast(unsigned int, v); }
__device__ __forceinline__ unsigned short f2bf(float f) {
  unsigned int u = __float_as_uint(f);
  u = (u + 0x7fffu + ((u >> 16) & 1u)) >> 16;
  return (unsigned short)u;
}

__device__ __forceinline__ float fdot2f(h2 a, h2 b, float c) {
#if __has_builtin(__builtin_amdgcn_fdot2)
  return __builtin_amdgcn_fdot2(a, b, c, false);
#else
  return fmaf((float)a.x, (float)b.x, fmaf((float)a.y, (float)b.y, c));
#endif
}

// ---------------- fused f32 -> bf16 convert for ALL weights (1 launch) ---------
__global__ void convert_all(const float* __restrict__ s0, ushort* __restrict__ d0,
                            const float* __restrict__ s1, ushort* __restrict__ d1,
                            const float* __restrict__ s2, ushort* __restrict__ d2,
                            const float* __restrict__ s3, ushort* __restrict__ d3,
                            const float* __restrict__ s4, ushort* __restrict__ d4,
                            const float* __restrict__ s5, ushort* __restrict__ d5) {
  int i = blockIdx.x * 256 + threadIdx.x;
  if (i < 589824) { d0[i] = f2bf(s0[i]); return; }
  i -= 589824;
  if (i < 196608) { d1[i] = f2bf(s1[i]); return; }
  i -= 196608;
  if (i < 393216) { d2[i] = f2bf(s2[i]); return; }
  i -= 393216;
  if (i < 393216) { d3[i] = f2bf(s3[i]); return; }
  i -= 393216;
  if (i < 262144) { d4[i] = f2bf(s4[i]); return; }
  i -= 262144;
  if (i < 65536) d5[i] = f2bf(s5[i]);
}

// ---------------- part encoder ----------------
__global__ void part_encoder(const float* __restrict__ parts, const float* __restrict__ Wpe1,
                             const float* __restrict__ bpe1, const float* __restrict__ Wpe2,
                             const float* __restrict__ bpe2, const float* __restrict__ pos,
                             float* __restrict__ x, ushort* __restrict__ xb) {
  __shared__ float prow[16];
  __shared__ float pe1[128];
  int row = blockIdx.x;
  int s = row & 255;
  int tid = threadIdx.x;  // 128
  if (tid < 16) prow[tid] = parts[row * 16 + tid];
  __syncthreads();
  float a = bpe1[tid];
#pragma unroll
  for (int k = 0; k < 16; ++k) a = fmaf(prow[k], Wpe1[tid * 16 + k], a);
  pe1[tid] = fmaxf(a, 0.0f);
  __syncthreads();
  float a2 = bpe2[tid];
  for (int k = 0; k < 128; ++k) a2 = fmaf(pe1[k], Wpe2[tid * 128 + k], a2);
  x[(size_t)row * 256 + tid] = a2;
  xb[(size_t)row * 256 + tid] = f2bf(a2);
  if (tid < 64) {
    float p = pos[s * 64 + tid];
    x[(size_t)row * 256 + 128 + tid] = p;
    xb[(size_t)row * 256 + 128 + tid] = f2bf(p);
    x[(size_t)row * 256 + 192 + tid] = 0.0f;
    xb[(size_t)row * 256 + 192 + tid] = 0;
  }
}

// ---------------- MFMA bf16 GEMM, 1-wave blocks (16 rows x 64 cols per block) --
// R14: 64-thread blocks quadruple the grid -> all 256 CUs active, 2-6
// independent waves/CU interleave the serial K-loop load latencies (old
// 256-thr grids left half the CUs idle at (4,32)).
// OUT: 0 = f32 C[m][n]; 1 = bf16 C[m][n]; 3 = f32 TRANSPOSED penT[(b*256+n)*256 + m%256]
template <int ACT, int OUT>
__global__ __launch_bounds__(64) void gemm_bf16(
    const ushort* __restrict__ A, const ushort* __restrict__ Wt,
    const float* __restrict__ bias1, const float* __restrict__ bias2,
    void* __restrict__ Cout, int N, int K) {
  int lane = threadIdx.x;          // 0..63
  int m0 = blockIdx.y * 16;
  int n0 = blockIdx.x * 64;
  int r15 = lane & 15;
  int kg = lane >> 4;
  f32x4 acc0 = {0.f, 0.f, 0.f, 0.f}, acc1 = acc0, acc2 = acc0, acc3 = acc0;
  const ushort* arow = A + (size_t)(m0 + r15) * K + kg * 8;
  const ushort* w0 = Wt + (size_t)(n0 + r15) * K + kg * 8;
  const ushort* w1 = w0 + (size_t)16 * K;
  const ushort* w2 = w0 + (size_t)32 * K;
  const ushort* w3 = w0 + (size_t)48 * K;
  for (int k0 = 0; k0 < K; k0 += 32) {
    bf16x8 af = *(const bf16x8*)(arow + k0);
    bf16x8 b0 = *(const bf16x8*)(w0 + k0);
    bf16x8 b1 = *(const bf16x8*)(w1 + k0);
    bf16x8 b2 = *(const bf16x8*)(w2 + k0);
    bf16x8 b3 = *(const bf16x8*)(w3 + k0);
    acc0 = __builtin_amdgcn_mfma_f32_16x16x32_bf16(af, b0, acc0, 0, 0, 0);
    acc1 = __builtin_amdgcn_mfma_f32_16x16x32_bf16(af, b1, acc1, 0, 0, 0);
    acc2 = __builtin_amdgcn_mfma_f32_16x16x32_bf16(af, b2, acc2, 0, 0, 0);
    acc3 = __builtin_amdgcn_mfma_f32_16x16x32_bf16(af, b3, acc3, 0, 0, 0);
  }
#pragma unroll
  for (int nn = 0; nn < 4; ++nn) {
    f32x4 a = (nn == 0) ? acc0 : (nn == 1) ? acc1 : (nn == 2) ? acc2 : acc3;
    int n = n0 + nn * 16 + r15;
    float bsum = bias1[n] + (bias2 ? bias2[n] : 0.0f);
    if (OUT == 3) {
      int b = m0 >> 8;
      int mloc = (m0 & 255) + kg * 4;
      float4 o4 = {a[0] + bsum, a[1] + bsum, a[2] + bsum, a[3] + bsum};
      *(float4*)&((float*)Cout)[((size_t)(b * 256 + n)) * 256 + mloc] = o4;
    } else {
#pragma unroll
      for (int r = 0; r < 4; ++r) {
        int m = m0 + kg * 4 + r;
        float v = a[r] + bsum;
        if (ACT == 1) v = fmaxf(v, 0.0f);
        if (OUT == 1)
          ((ushort*)Cout)[(size_t)m * N + n] = f2bf(v);
        else
          ((float*)Cout)[(size_t)m * N + n] = v;
      }
    }
  }
}

// ---------------- attention (f32 in, bf16 out) ----------------
__global__ void attn_kernel(const float* __restrict__ qkv, ushort* __restrict__ attout) {
  extern __shared__ float sm[];
  float* kl = sm;
  float* ql = sm + 256 * 33;
  float* sc = sm + 256 * 33 + 32 * 33;
  int qt = blockIdx.x, h = blockIdx.y, b = blockIdx.z;
  int tid = threadIdx.x;  // 256
  {
    int j = tid;
    const float* src = qkv + (size_t)(b * 256 + j) * 768 + 256 + h * 32;
#pragma unroll
    for (int d = 0; d < 32; d += 4) {
      float4 v = *(const float4*)(src + d);
      kl[j * 33 + d] = v.x; kl[j * 33 + d + 1] = v.y; kl[j * 33 + d + 2] = v.z; kl[j * 33 + d + 3] = v.w;
    }
  }
  {
    int i = tid >> 3, d4 = (tid & 7) * 4;
    const float* src = qkv + (size_t)(b * 256 + qt * 32 + i) * 768 + h * 32;
    float4 v = *(const float4*)(src + d4);
    ql[i * 33 + d4] = v.x; ql[i * 33 + d4 + 1] = v.y; ql[i * 33 + d4 + 2] = v.z; ql[i * 33 + d4 + 3] = v.w;
  }
  __syncthreads();
  int i = tid >> 3, c = tid & 7;
  const float scale = 0.17677669529663687f;
  float sv[32];
  float mx = -1e30f;
  for (int jj = 0; jj < 32; ++jj) {
    int j = jj * 8 + c;
    float s = 0.0f;
#pragma unroll
    for (int d = 0; d < 32; ++d) s = fmaf(ql[i * 33 + d], kl[j * 33 + d], s);
    s *= scale;
    sv[jj] = s;
    mx = fmaxf(mx, s);
  }
  mx = fmaxf(mx, __shfl_xor(mx, 1));
  mx = fmaxf(mx, __shfl_xor(mx, 2));
  mx = fmaxf(mx, __shfl_xor(mx, 4));
  float sum = 0.0f;
  for (int jj = 0; jj < 32; ++jj) {
    float p = __expf(sv[jj] - mx);
    sc[i * 257 + jj * 8 + c] = p;
    sum += p;
  }
  sum += __shfl_xor(sum, 1);
  sum += __shfl_xor(sum, 2);
  sum += __shfl_xor(sum, 4);
  float inv = 1.0f / sum;
  __syncthreads();
  float a0 = 0, a1 = 0, a2 = 0, a3 = 0;
  int d0 = c * 4;
  const float* vbase = qkv + 512 + h * 32 + d0;
  for (int j = 0; j < 256; ++j) {
    float p = sc[i * 257 + j];
    float4 v = *(const float4*)(vbase + (size_t)(b * 256 + j) * 768);
    a0 = fmaf(p, v.x, a0); a1 = fmaf(p, v.y, a1); a2 = fmaf(p, v.z, a2); a3 = fmaf(p, v.w, a3);
  }
  int orow = b * 256 + qt * 32 + i;
  ushort4 o4;
  o4.x = f2bf(a0 * inv); o4.y = f2bf(a1 * inv); o4.z = f2bf(a2 * inv); o4.w = f2bf(a3 * inv);
  *(ushort4*)&attout[(size_t)orow * 256 + h * 32 + d0] = o4;
}

// ---------------- LayerNorm(x + o) ----------------
__global__ void ln_residual(float* __restrict__ x, const float* __restrict__ o,
                            const float* __restrict__ g, const float* __restrict__ bt,
                            ushort* __restrict__ xb) {
  int row = blockIdx.x, tid = threadIdx.x;  // 256
  float e = x[(size_t)row * 256 + tid] + o[(size_t)row * 256 + tid];
  float s = e, q = e * e;
#pragma unroll
  for (int off = 32; off >= 1; off >>= 1) {
    s += __shfl_xor(s, off);
    q += __shfl_xor(q, off);
  }
  __shared__ float ps[4], pq[4];
  int wid = tid >> 6, lane = tid & 63;
  if (lane == 0) { ps[wid] = s; pq[wid] = q; }
  __syncthreads();
  float St = ps[0] + ps[1] + ps[2] + ps[3];
  float Qt = pq[0] + pq[1] + pq[2] + pq[3];
  float mean = St * (1.0f / 256.0f);
  float var = Qt * (1.0f / 256.0f) - mean * mean;
  float y = (e - mean) * rsqrtf(var + 1e-5f) * g[tid] + bt[tid];
  x[(size_t)row * 256 + tid] = y;
  xb[(size_t)row * 256 + tid] = f2bf(y);
}

// ---------------- gather dec_in ----------------
__global__ void gather_dec_in(const ushort* __restrict__ encb, const int* __restrict__ ts,
                              ushort* __restrict__ dec_in) {
  int bx = blockIdx.x;
  int t = bx >> 3, b = bx & 7;
  int tid = threadIdx.x;  // 64
  ushort4 v = {0, 0, 0, 0};
  if (t > 0) {
    int sidx = ts[b * 256 + t - 1];
    v = *(const ushort4*)&encb[((size_t)(b * 256 + sidx)) * 256 + tid * 4];
  }
  *(ushort4*)&dec_in[(size_t)bx * 256 + tid * 4] = v;
}

// ---------------- LSTM scan v512 (PROVEN; single-CU bf16 storage floor) -------
// 479 us = ~1.87 us/step, LDS-b128-issue bound (48 b128/wave/step x 8 waves x
// ~12 cyc = 4600 cyc/step, matches measurement). fp8/int8 recurrence is
// numerically dead (est. absmax 0.05+); cross-CU sync costs >=2 us/step.
__global__ __attribute__((amdgpu_flat_work_group_size(512, 512), amdgpu_waves_per_eu(1, 1)))
void lstm_scan512(const float* __restrict__ Xw, const float* __restrict__ Whh,
                  ushort* __restrict__ dec_out) {
  extern __shared__ char smem[];
  uint4* wlds = (uint4*)smem;                 // [8][1024] uint4 = 128 KB
  h2* hbuf = (h2*)(smem + 131072);            // [2][128] h2
  int b = blockIdx.x;
  int t0 = threadIdx.x;        // 0..511
  int u = t0 >> 1, p = t0 & 1;
  int rA = u + 256 * p;
  int rB = u + 512 + 256 * p;

  h2 w0[96], w1[96];
  {
    const float4* sA = (const float4*)(Whh + (size_t)rA * 256);
    const float4* sB = (const float4*)(Whh + (size_t)rB * 256);
#pragma unroll
    for (int k = 0; k < 48; ++k) {
      float4 v = sA[k];
      w0[2 * k] = cvt2(v.x, v.y);
      w0[2 * k + 1] = cvt2(v.z, v.w);
    }
#pragma unroll
    for (int k = 0; k < 48; ++k) {
      float4 v = sB[k];
      w1[2 * k] = cvt2(v.x, v.y);
      w1[2 * k + 1] = cvt2(v.z, v.w);
    }
#pragma unroll
    for (int qc = 0; qc < 8; ++qc) {
      float4 vA0 = sA[48 + 2 * qc], vA1 = sA[48 + 2 * qc + 1];
      float4 vB0 = sB[48 + 2 * qc], vB1 = sB[48 + 2 * qc + 1];
      uint4 uA, uB;
      uA.x = bcu(cvt2(vA0.x, vA0.y)); uA.y = bcu(cvt2(vA0.z, vA0.w));
      uA.z = bcu(cvt2(vA1.x, vA1.y)); uA.w = bcu(cvt2(vA1.z, vA1.w));
      uB.x = bcu(cvt2(vB0.x, vB0.y)); uB.y = bcu(cvt2(vB0.z, vB0.w));
      uB.z = bcu(cvt2(vB1.x, vB1.y)); uB.w = bcu(cvt2(vB1.z, vB1.w));
      wlds[qc * 1024 + rA] = uA;
      wlds[qc * 1024 + rB] = uB;
    }
  }
  if (t0 < 128) ((uint4*)hbuf)[t0 & 63] = make_uint4(0, 0, 0, 0);
  float c = 0.0f;
  float xnA = Xw[(size_t)b * 1024 + rA];
  float xnB = Xw[(size_t)b * 1024 + rB];
  __syncthreads();

  for (int t = 0; t < 256; ++t) {
    float xwA = xnA, xwB = xnB;
    if (t < 255) {
      const float* xp = Xw + (size_t)((t + 1) * 8 + b) * 1024;
      xnA = xp[rA]; xnB = xp[rB];
    }
    const uint4* hb = (const uint4*)(hbuf + (size_t)(t & 1) * 128);
    float a0 = 0.0f, a1 = 0.0f;
#pragma unroll
    for (int q = 0; q < 24; ++q) {
      uint4 hv = hb[q];
      h2 hx = bch2(hv.x), hy = bch2(hv.y), hz = bch2(hv.z), hw = bch2(hv.w);
      a0 = fdot2f(w0[4 * q], hx, a0); a0 = fdot2f(w0[4 * q + 1], hy, a0);
      a0 = fdot2f(w0[4 * q + 2], hz, a0); a0 = fdot2f(w0[4 * q + 3], hw, a0);
      a1 = fdot2f(w1[4 * q], hx, a1); a1 = fdot2f(w1[4 * q + 1], hy, a1);
      a1 = fdot2f(w1[4 * q + 2], hz, a1); a1 = fdot2f(w1[4 * q + 3], hw, a1);
    }
#pragma unroll
    for (int qc = 0; qc < 8; ++qc) {
      uint4 hv = hb[24 + qc];
      h2 hx = bch2(hv.x), hy = bch2(hv.y), hz = bch2(hv.z), hw = bch2(hv.w);
      uint4 uA = wlds[qc * 1024 + rA];
      uint4 uB = wlds[qc * 1024 + rB];
      a0 = fdot2f(bch2(uA.x), hx, a0); a0 = fdot2f(bch2(uA.y), hy, a0);
      a0 = fdot2f(bch2(uA.z), hz, a0); a0 = fdot2f(bch2(uA.w), hw, a0);
      a1 = fdot2f(bch2(uB.x), hx, a1); a1 = fdot2f(bch2(uB.y), hy, a1);
      a1 = fdot2f(bch2(uB.z), hz, a1); a1 = fdot2f(bch2(uB.w), hw, a1);
    }
    a0 += xwA;
    a1 += xwB;
    float ev = sigf(a0) * tanhfast(a1);
    float ep = __shfl_xor(ev, 1);
    if (p == 1) {
      c = sigf(a0) * c + ep;
      float hv_ = sigf(a1) * tanhfast(c);
      ((_Float16*)(hbuf + (size_t)((t + 1) & 1) * 128))[u] = (_Float16)hv_;
      dec_out[((size_t)(b * 256 + t)) * 256 + u] = f2bf(hv_);
    }
    __syncthreads();
  }
}

// ---------------- pointer logits ----------------
__global__ void pointer_kernel(const float* __restrict__ pd, const float* __restrict__ penT,
                               const float* __restrict__ vptr, float* __restrict__ out) {
  __shared__ float pdr[256];
  __shared__ float vl[256];
  int bx = blockIdx.x;
  int b = bx >> 8;
  int tid = threadIdx.x;  // 256
  pdr[tid] = pd[(size_t)bx * 256 + tid];
  vl[tid] = vptr[tid];
  __syncthreads();
  const float* pT = penT + (size_t)b * 256 * 256;
  float acc = 0.0f;
  for (int h = 0; h < 256; ++h) {
    acc = fmaf(vl[h], tanhfast(pdr[h] + pT[(size_t)h * 256 + tid]), acc);
  }
  out[(size_t)bx * 256 + tid] = acc;
}

extern "C" void kernel_launch(void* const* d_in, const int* in_sizes, int n_in,
                              void* d_out, int out_size, void* d_ws, size_t ws_size,
                              hipStream_t stream) {
  const float* parts = (const float*)d_in[0];
  const int* ts = (const int*)d_in[1];
  const float* Wpe1 = (const float*)d_in[2];
  const float* bpe1 = (const float*)d_in[3];
  const float* Wpe2 = (const float*)d_in[4];
  const float* bpe2 = (const float*)d_in[5];
  const float* pos = (const float*)d_in[6];
  const float* Wqkv = (const float*)d_in[7];
  const float* bqkv = (const float*)d_in[8];
  const float* Wo = (const float*)d_in[9];
  const float* bo = (const float*)d_in[10];
  const float* ln1g = (const float*)d_in[11];
  const float* ln1b = (const float*)d_in[12];
  const float* W1f = (const float*)d_in[13];
  const float* b1f = (const float*)d_in[14];
  const float* W2f = (const float*)d_in[15];
  const float* b2f = (const float*)d_in[16];
  const float* ln2g = (const float*)d_in[17];
  const float* ln2b = (const float*)d_in[18];
  const float* Wih = (const float*)d_in[19];
  const float* Whh = (const float*)d_in[20];
  const float* bih = (const float*)d_in[21];
  const float* bhh = (const float*)d_in[22];
  const float* Wp = (const float*)d_in[23];
  const float* bp = (const float*)d_in[24];
  const float* vptr = (const float*)d_in[25];
  float* out = (float*)d_out;

  // ---- workspace layout (f32-slot units) ----
  float* W = (float*)d_ws;
  float* xbuf = W;                            // [2048,256] f32, live all
  ushort* xbf = (ushort*)(W + 524288);        // [2048,256] bf16, live all
  float* SCR = W + 786432;                    // 2097152 slots scratch
  float* qkvb = SCR;                          //   encoder: [2048,768] f32
  float* obuf = SCR + 1572864;                //   encoder: [2048,256] f32
  float* Xw = SCR;                            //   decoder: [2048,1024] f32
  float* pdb = SCR;                           //   tail: [2048,256] f32
  float* penTb = SCR + 1048576;               //   tail: [8,256,256] f32 transposed
  ushort* attbf = (ushort*)(W + 2883584);     // [2048,256] bf16 (encoder)
  ushort* ffbf = (ushort*)(W + 3145728);      // [2048,512] bf16 (encoder)
  ushort* dec_inbf = (ushort*)(W + 3145728);  //   decoder: [2048,256] bf16
  ushort* dec_outbf = (ushort*)(W + 3407872); //   decoder: [2048,256] bf16
  ushort* wqkvbf = (ushort*)(W + 3670016);    // 589824 bf16
  ushort* wobf   = (ushort*)(W + 3964928);    // 196608
  ushort* w1fbf  = (ushort*)(W + 4063232);    // 393216
  ushort* w2fbf  = (ushort*)(W + 4259840);    // 393216
  ushort* wihbf  = (ushort*)(W + 4456448);    // 262144
  ushort* wpbf   = (ushort*)(W + 4587520);    // 65536

  const int attnLDS = (256 * 33 + 32 * 33 + 32 * 257) * 4;  // 70912 B
  const int scan512LDS = 131072 + 1024;                     // 132096 B
  hipFuncSetAttribute((const void*)attn_kernel, hipFuncAttributeMaxDynamicSharedMemorySize, attnLDS);
  hipFuncSetAttribute((const void*)lstm_scan512, hipFuncAttributeMaxDynamicSharedMemorySize, scan512LDS);

  // fused weight conversion (1 launch)
  convert_all<<<7424, 256, 0, stream>>>(Wqkv, wqkvbf, Wo, wobf, W1f, w1fbf,
                                        W2f, w2fbf, Wih, wihbf, Wp, wpbf);

  part_encoder<<<2048, 128, 0, stream>>>(parts, Wpe1, bpe1, Wpe2, bpe2, pos, xbuf, xbf);
  for (int l = 0; l < 3; ++l) {
    gemm_bf16<0, 0><<<dim3(12, 128), 64, 0, stream>>>(xbf, wqkvbf + (size_t)l * 196608,
                                                      bqkv + l * 768, nullptr, qkvb, 768, 256);
    attn_kernel<<<dim3(8, 8, 8), 256, attnLDS, stream>>>(qkvb, attbf);
    gemm_bf16<0, 0><<<dim3(4, 128), 64, 0, stream>>>(attbf, wobf + (size_t)l * 65536,
                                                     bo + l * 256, nullptr, obuf, 256, 256);
    ln_residual<<<2048, 256, 0, stream>>>(xbuf, obuf, ln1g + l * 256, ln1b + l * 256, xbf);
    gemm_bf16<1, 1><<<dim3(8, 128), 64, 0, stream>>>(xbf, w1fbf + (size_t)l * 131072,
                                                     b1f + l * 512, nullptr, ffbf, 512, 256);
    gemm_bf16<0, 0><<<dim3(4, 128), 64, 0, stream>>>(ffbf, w2fbf + (size_t)l * 131072,
                                                     b2f + l * 256, nullptr, obuf, 256, 512);
    ln_residual<<<2048, 256, 0, stream>>>(xbuf, obuf, ln2g + l * 256, ln2b + l * 256, xbf);
  }
  gather_dec_in<<<2048, 64, 0, stream>>>(xbf, ts, dec_inbf);
  gemm_bf16<0, 0><<<dim3(16, 128), 64, 0, stream>>>(dec_inbf, wihbf, bih, bhh, Xw, 1024, 256);
  lstm_scan512<<<8, 512, scan512LDS, stream>>>(Xw, Whh, dec_outbf);
  gemm_bf16<0, 0><<<dim3(4, 128), 64, 0, stream>>>(dec_outbf, wpbf, bp, nullptr, pdb, 256, 256);
  gemm_bf16<0, 3><<<dim3(4, 128), 64, 0, stream>>>(xbf, wpbf, bp, nullptr, penTb, 256, 256);
  pointer_kernel<<<2048, 256, 0, stream>>>(pdb, penTb, vptr, out);
}